// Round 4
// baseline (144.922 us; speedup 1.0000x reference)
//
#include <hip/hip_runtime.h>
#include <stdint.h>

// Problem constants
#define B_SZ 8
#define T_SZ 1024
#define DM   768
#define NH   12
#define DH   64
#define NTOK (B_SZ * T_SZ)   // 8192
#define NOUT (NTOK * DM)     // 6291456
#define INF  __builtin_inff()

typedef unsigned short u16;
typedef __attribute__((ext_vector_type(8))) short short8;   // 8 bf16 (4 VGPRs) MFMA frag
typedef __attribute__((ext_vector_type(4))) short short4v;
typedef __attribute__((ext_vector_type(4))) float f32x4;

#define MFMA16x16x32 __builtin_amdgcn_mfma_f32_16x16x32_bf16

__device__ __forceinline__ u16 f2bf(float f) {
    unsigned u = __builtin_bit_cast(unsigned, f);
    u += 0x7fffu + ((u >> 16) & 1u);   // RNE
    return (u16)(u >> 16);
}

__device__ __forceinline__ f32x4 max4(f32x4 a, f32x4 b) {
    f32x4 r; r.x = fmaxf(a.x, b.x); r.y = fmaxf(a.y, b.y);
    r.z = fmaxf(a.z, b.z); r.w = fmaxf(a.w, b.w); return r;
}
__device__ __forceinline__ f32x4 add4(f32x4 a, f32x4 b) {
    f32x4 r; r.x = a.x + b.x; r.y = a.y + b.y;
    r.z = a.z + b.z; r.w = a.w + b.w; return r;
}

// CK-proven pattern: integer-cast to AS1/AS3 pointers for the direct-to-LDS load.
__device__ __forceinline__ void gload16(const void* g, void* l) {
    __builtin_amdgcn_global_load_lds(
        (const __attribute__((address_space(1))) unsigned int*)(unsigned long long)(uintptr_t)g,
        (__attribute__((address_space(3))) unsigned int*)(unsigned int)(uintptr_t)l,
        16, 0, 0);
}

// ---------------- fp32 -> bf16 elementwise ----------------
__global__ __launch_bounds__(256) void cvt_bf16_kernel(const float* __restrict__ in,
                                                       u16* __restrict__ out, int n) {
    int i = (blockIdx.x * 256 + threadIdx.x) * 4;
    if (i >= n) return;
    f32x4 v = *(const f32x4*)(in + i);
    short4v o;
    o.x = (short)f2bf(v.x); o.y = (short)f2bf(v.y);
    o.z = (short)f2bf(v.z); o.w = (short)f2bf(v.w);
    *(short4v*)(out + i) = o;
}

// ---------------- transpose fp32 [R][C] -> bf16 [C][R] ----------------
__global__ __launch_bounds__(256) void transpose_bf16_kernel(const float* __restrict__ in,
                                                             u16* __restrict__ out,
                                                             int R, int C) {
    __shared__ float tile[32][33];
    int tx = threadIdx.x & 31, ty = threadIdx.x >> 5;   // 32 x 8
    int c0 = blockIdx.x * 32, r0 = blockIdx.y * 32;
    for (int i = ty; i < 32; i += 8)
        tile[i][tx] = in[(size_t)(r0 + i) * C + c0 + tx];
    __syncthreads();
    for (int i = ty; i < 32; i += 8)
        out[(size_t)(c0 + i) * R + r0 + tx] = f2bf(tile[tx][i]);
}

// ---------------- per-head V transpose: fp32 [96][1024][64] -> bf16 [96][64][1024] ----------------
__global__ __launch_bounds__(256) void transpose_v_kernel(const float* __restrict__ in,
                                                          u16* __restrict__ out) {
    __shared__ float tile[32][33];
    const int head = blockIdx.z;
    const int t0 = blockIdx.x * 32, d0 = blockIdx.y * 32;
    const float* ip = in + (size_t)head * 65536;
    u16* op = out + (size_t)head * 65536;
    int tx = threadIdx.x & 31, ty = threadIdx.x >> 5;
    for (int i = ty; i < 32; i += 8)
        tile[i][tx] = ip[(size_t)(t0 + i) * 64 + d0 + tx];
    __syncthreads();
    for (int i = ty; i < 32; i += 8)
        op[(size_t)(d0 + i) * 1024 + t0 + tx] = f2bf(tile[tx][i]);
}

// ---------------- bf16 GEMM, K=768, 128x128 tile, dbuf 2-phase + XOR swizzle ----------------
// A [M][768] bf16 row-major, BT [N][768] bf16 (B transposed).
// LDS tiles [128 rows][4 chunks of 16B], chunk phys slot = logical ^ (row&3)
// (pre-swizzled on the global_load_lds SOURCE; same XOR on ds_read -> 2-way max).
// Double-buffered: STAGE(k+1) issues before compute(k); one barrier per K-step.
template <int EPI>
__global__ __launch_bounds__(256, 4) void gemm_k768_kernel(
    const u16* __restrict__ A, const u16* __restrict__ BT, const float* __restrict__ bias,
    u16* __restrict__ qbf, u16* __restrict__ kbf,
    float* __restrict__ outK, float* __restrict__ outV, float* __restrict__ outP)
{
    __shared__ alignas(16) u16 As[2][128 * 32];   // 8 KB each
    __shared__ alignas(16) u16 Bs[2][128 * 32];
    const int t   = threadIdx.x;
    const int wid = t >> 6, l = t & 63;
    const int lr  = l & 15, g = l >> 4;

    // XCD-aware swizzle (T1): nwg divisible by 8 for both instantiations
    const int nwgx = gridDim.x;
    const int nwg  = nwgx * gridDim.y;
    const int fid  = blockIdx.y * nwgx + blockIdx.x;
    const int swz  = (fid & 7) * (nwg >> 3) + (fid >> 3);
    const int m0   = (swz % nwgx) * 128, n0 = (swz / nwgx) * 128;
    const int wm   = (wid >> 1) * 64, wn = (wid & 1) * 64;

    // staging: thread t carries row srow (and srow+64), phys slot t&3,
    // logical chunk = (t&3) ^ (srow&3)   ((srow+64)&3 == srow&3)
    const int srow = t >> 2;
    const int sch  = (t & 3) ^ (srow & 3);
    const u16* ga0 = A  + (size_t)(m0 + srow) * 768 + sch * 8;
    const u16* ga1 = A  + (size_t)(m0 + 64 + srow) * 768 + sch * 8;
    const u16* gb0 = BT + (size_t)(n0 + srow) * 768 + sch * 8;
    const u16* gb1 = BT + (size_t)(n0 + 64 + srow) * 768 + sch * 8;

#define GSTAGE(buf, k0) do {                              \
        gload16(ga0 + (k0), As[buf] + t * 8);             \
        gload16(ga1 + (k0), As[buf] + 2048 + t * 8);      \
        gload16(gb0 + (k0), Bs[buf] + t * 8);             \
        gload16(gb1 + (k0), Bs[buf] + 2048 + t * 8);      \
    } while (0)

    // fragment read column offset (u16): logical chunk g at row lr-group
    const int fco = (g ^ (lr & 3)) * 8;

    f32x4 acc[4][4] = {};
    GSTAGE(0, 0);
    __syncthreads();
    int cur = 0;
    #pragma unroll 1
    for (int k0 = 32; k0 <= 768; k0 += 32) {
        if (k0 < 768) GSTAGE(cur ^ 1, k0);
        const u16* aB = As[cur];
        const u16* bB = Bs[cur];
        short8 af[4], bfr[4];
        #pragma unroll
        for (int i = 0; i < 4; ++i)
            af[i] = *(const short8*)(aB + (wm + i * 16 + lr) * 32 + fco);
        #pragma unroll
        for (int j = 0; j < 4; ++j)
            bfr[j] = *(const short8*)(bB + (wn + j * 16 + lr) * 32 + fco);
        __builtin_amdgcn_s_setprio(1);
        #pragma unroll
        for (int i = 0; i < 4; ++i)
            #pragma unroll
            for (int j = 0; j < 4; ++j)
                acc[i][j] = MFMA16x16x32(af[i], bfr[j], acc[i][j], 0, 0, 0);
        __builtin_amdgcn_s_setprio(0);
        __syncthreads();   // drains staged loads; all waves done with buf cur
        cur ^= 1;
    }
#undef GSTAGE

    // C/D layout: col = lane&15, row = (lane>>4)*4 + reg  [verified m89/m91]
    #pragma unroll
    for (int j = 0; j < 4; ++j) {
        const int n = n0 + wn + j * 16 + lr;
        const float bn = bias[n];
        if (EPI == 0) {
            const int which = n / 768;           // 0=Q,1=K,2=V (wave-uniform)
            const int hd = n - which * 768;
            const int h = hd >> 6, dd = hd & 63;
            #pragma unroll
            for (int i = 0; i < 4; ++i) {
                #pragma unroll
                for (int r = 0; r < 4; ++r) {
                    const int m = m0 + wm + i * 16 + g * 4 + r;
                    const int b = m >> 10, tt = m & 1023;
                    const int idx = ((b * 12 + h) * 1024 + tt) * 64 + dd;
                    const float v = acc[i][j][r] + bn;
                    if (which == 0) {
                        // fold 1/sqrt(64) and log2(e) so attn exp2 needs no mul
                        qbf[idx] = f2bf(v * (0.125f * 1.44269504f));
                    } else if (which == 1) {
                        outK[idx] = v; kbf[idx] = f2bf(v);
                    } else {
                        outV[idx] = v;   // V^T bf16 produced by transpose_v_kernel
                    }
                }
            }
        } else {
            #pragma unroll
            for (int i = 0; i < 4; ++i)
                #pragma unroll
                for (int r = 0; r < 4; ++r) {
                    const int m = m0 + wm + i * 16 + g * 4 + r;
                    outP[(size_t)m * 768 + n] = acc[i][j][r] + bn;
                }
        }
    }
}

// ---------------- causal flash attention, LDS-staged 2-phase pipeline ----------------
// grid (96, 8), 4 waves. Block y handles q-tiles y and 15-y (uniform 17 rounds).
// K/V tiles (64 kt x 64 d bf16, 8 KB each) double-buffered in LDS via
// global_load_lds with XOR chunk-swizzle (chunk ^= row&7) applied on the GLOBAL
// source and on the ds_read address (both-sides rule). Wave owns 16 q columns.
__global__ __launch_bounds__(256, 3) void attn_kernel(
    const u16* __restrict__ Qb, const u16* __restrict__ Kb,
    const u16* __restrict__ Vt, u16* __restrict__ Ob)
{
    __shared__ alignas(16) u16 Ks[2][4096];     // [64 kt][8 chunks of 8 u16], swizzled
    __shared__ alignas(16) u16 Vs[2][4096];     // [64 d ][8 chunks of 8 u16], swizzled
    __shared__ alignas(16) u16 Pl[4][16 * 72];  // per-wave P: 16 q x (64+8 pad) u16
    const int bh = blockIdx.x;
    const int t = threadIdx.x;
    const int wid = t >> 6, l = t & 63;
    const int c = l & 15, g = l >> 4;
    u16* P = Pl[wid];
    const u16* Kp = Kb + (size_t)bh * 65536;    // [T][64]
    const u16* Vp = Vt + (size_t)bh * 65536;    // [64][T]
    const int b = bh / 12, h = bh - (bh / 12) * 12;

    const int srow = t >> 3;
    const int sch  = (t & 7) ^ (srow & 7);
    const u16* Ksrc0 = Kp + (size_t)srow * 64 + sch * 8;
    const u16* Ksrc1 = Kp + (size_t)(srow + 32) * 64 + sch * 8;
    const u16* Vsrc0 = Vp + (size_t)srow * 1024 + sch * 8;
    const u16* Vsrc1 = Vp + (size_t)(srow + 32) * 1024 + sch * 8;

    // fragment read offsets (u16): row c (within 16-row subtile), logical chunk g / g+4
    const int fo0 = c * 64 + ((g ^ (c & 7)) * 8);
    const int fo1 = c * 64 + (((g + 4) ^ (c & 7)) * 8);

#define STAGE(buf, kt0) do {                                        \
        gload16(Ksrc0 + (size_t)(kt0) * 64, Ks[buf] + t * 8);       \
        gload16(Ksrc1 + (size_t)(kt0) * 64, Ks[buf] + 2048 + t * 8);\
        gload16(Vsrc0 + (kt0),              Vs[buf] + t * 8);       \
        gload16(Vsrc1 + (kt0),              Vs[buf] + 2048 + t * 8);\
    } while (0)

    #pragma unroll 1
    for (int pass = 0; pass < 2; ++pass) {
        const int tile = pass ? (15 - blockIdx.y) : blockIdx.y;
        const int qbase = tile * 64 + wid * 16;
        const int qg = qbase + c;                // this lane's q column
        const u16* Qp = Qb + ((size_t)bh * 1024 + qg) * 64 + g * 8;
        const short8 bq0 = *(const short8*)(Qp);
        const short8 bq1 = *(const short8*)(Qp + 32);

        f32x4 oacc[4] = {};
        float mrow = -INF, lpart = 0.f;
        const int nb = tile + 1;                 // 64-wide KV blocks

        STAGE(0, 0);
        __syncthreads();
        int cur = 0;

        #pragma unroll 1
        for (int kb = 0; kb < nb; ++kb) {
            if (kb + 1 < nb) STAGE(cur ^ 1, (kb + 1) << 6);
            const u16* kB = Ks[cur];
            const u16* vB = Vs[cur];
            short8 af0[4], af1[4], vf0[4], vf1[4];
            #pragma unroll
            for (int j = 0; j < 4; ++j) {
                af0[j] = *(const short8*)(kB + j * 1024 + fo0);
                af1[j] = *(const short8*)(kB + j * 1024 + fo1);
            }
            #pragma unroll
            for (int dt = 0; dt < 4; ++dt) {
                vf0[dt] = *(const short8*)(vB + dt * 1024 + fo0);
                vf1[dt] = *(const short8*)(vB + dt * 1024 + fo1);
            }
            // QK^T: D[kt][q], s[j] covers kt rows j*16 + g*4 + r
            f32x4 s[4] = {};
            __builtin_amdgcn_s_setprio(1);
            #pragma unroll
            for (int j = 0; j < 4; ++j) {
                s[j] = MFMA16x16x32(af0[j], bq0, s[j], 0, 0, 0);
                s[j] = MFMA16x16x32(af1[j], bq1, s[j], 0, 0, 0);
            }
            __builtin_amdgcn_s_setprio(0);
            if (kb == nb - 1) {                  // only diagonal block masks
                const int kt0 = kb << 6;
                #pragma unroll
                for (int j = 0; j < 4; ++j)
                    #pragma unroll
                    for (int r = 0; r < 4; ++r)
                        if (kt0 + j * 16 + g * 4 + r > qg) s[j][r] = -INF;
            }
            // softmax (scores already in log2 units); tree max
            f32x4 mm = max4(max4(s[0], s[1]), max4(s[2], s[3]));
            float tm = fmaxf(fmaxf(mm.x, mm.y), fmaxf(mm.z, mm.w));
            tm = fmaxf(tm, __shfl_xor(tm, 16));
            tm = fmaxf(tm, __shfl_xor(tm, 32));
            // defer-max (T13): skip rescale while growth <= 8 (log2 units; P <= 256)
            const bool keep = (__all(tm <= mrow + 8.f) != 0);
            const float mnew = keep ? mrow : fmaxf(mrow, tm);
            if (!keep) {
                const float sc = exp2f(mrow - mnew);
                mrow = mnew;
                lpart *= sc;
                #pragma unroll
                for (int dt = 0; dt < 4; ++dt) {
                    oacc[dt][0] *= sc; oacc[dt][1] *= sc;
                    oacc[dt][2] *= sc; oacc[dt][3] *= sc;
                }
            }
            f32x4 p[4];
            #pragma unroll
            for (int j = 0; j < 4; ++j) {
                p[j].x = exp2f(s[j].x - mnew); p[j].y = exp2f(s[j].y - mnew);
                p[j].z = exp2f(s[j].z - mnew); p[j].w = exp2f(s[j].w - mnew);
            }
            f32x4 ps = add4(add4(p[0], p[1]), add4(p[2], p[3]));
            lpart += (ps.x + ps.y) + (ps.z + ps.w);   // per-lane partial (g-reduce deferred)
            // P[q=c][kt] bf16 -> LDS (row stride 72 u16 = 144 B, 2-way conflicts only)
            #pragma unroll
            for (int j = 0; j < 4; ++j) {
                short4v w;
                w.x = (short)f2bf(p[j].x); w.y = (short)f2bf(p[j].y);
                w.z = (short)f2bf(p[j].z); w.w = (short)f2bf(p[j].w);
                *(short4v*)(P + c * 72 + j * 16 + g * 4) = w;
            }
            const short8 pf0 = *(const short8*)(P + c * 72 + g * 8);
            const short8 pf1 = *(const short8*)(P + c * 72 + 32 + g * 8);
            // PV: A = V^T rows (d), B = P^T -> D[d][q]
            __builtin_amdgcn_s_setprio(1);
            #pragma unroll
            for (int dt = 0; dt < 4; ++dt) {
                oacc[dt] = MFMA16x16x32(vf0[dt], pf0, oacc[dt], 0, 0, 0);
                oacc[dt] = MFMA16x16x32(vf1[dt], pf1, oacc[dt], 0, 0, 0);
            }
            __builtin_amdgcn_s_setprio(0);
            __syncthreads();   // drains staging (vmcnt 0) + all waves done with buf cur
            cur ^= 1;
        }
        float lsum = lpart;
        lsum += __shfl_xor(lsum, 16);
        lsum += __shfl_xor(lsum, 32);
        const float li = 1.f / lsum;             // lane-local (col=q layout)
        #pragma unroll
        for (int dt = 0; dt < 4; ++dt) {
            short4v o;
            o.x = (short)f2bf(oacc[dt][0] * li);
            o.y = (short)f2bf(oacc[dt][1] * li);
            o.z = (short)f2bf(oacc[dt][2] * li);
            o.w = (short)f2bf(oacc[dt][3] * li);
            *(short4v*)(Ob + (size_t)(b * 1024 + qg) * 768 + h * 64 + dt * 16 + g * 4) = o;
        }
    }
#undef STAGE
}

extern "C" void kernel_launch(void* const* d_in, const int* in_sizes, int n_in,
                              void* d_out, int out_size, void* d_ws, size_t ws_size,
                              hipStream_t stream) {
    const float* hs = (const float*)d_in[0];   // [8,1024,768]
    const float* Wa = (const float*)d_in[1];   // [768,2304]
    const float* ba = (const float*)d_in[2];   // [2304]
    const float* Wp = (const float*)d_in[3];   // [768,768]
    const float* bp = (const float*)d_in[4];   // [768]
    float* out = (float*)d_out;                // out | K | V  (each NOUT fp32)

    u16* ws  = (u16*)d_ws;
    u16* Xbf = ws;                             // [8192][768]
    u16* WaT = Xbf + NOUT;                     // [2304][768]
    u16* WpT = WaT + 768 * 2304;               // [768][768]
    u16* Qbf = WpT + 768 * 768;                // [B,H,T,64] (pre-scaled by 0.125*log2e)
    u16* Kbf = Qbf + NOUT;                     // [B,H,T,64]
    u16* VTb = Kbf + NOUT;                     // [B,H,64,T]
    u16* Obf = VTb + NOUT;                     // [8192][768]

    cvt_bf16_kernel<<<NOUT / 1024, 256, 0, stream>>>(hs, Xbf, NOUT);
    transpose_bf16_kernel<<<dim3(2304 / 32, 768 / 32), 256, 0, stream>>>(Wa, WaT, 768, 2304);
    transpose_bf16_kernel<<<dim3(768 / 32, 768 / 32), 256, 0, stream>>>(Wp, WpT, 768, 768);
    gemm_k768_kernel<0><<<dim3(64, 18), 256, 0, stream>>>(
        Xbf, WaT, ba, Qbf, Kbf, out + NOUT, out + 2 * (size_t)NOUT, nullptr);
    transpose_v_kernel<<<dim3(32, 2, 96), 256, 0, stream>>>(out + 2 * (size_t)NOUT, VTb);
    attn_kernel<<<dim3(96, 8), 256, 0, stream>>>(Qbf, Kbf, VTb, Obf);
    gemm_k768_kernel<1><<<dim3(64, 6), 256, 0, stream>>>(
        Obf, WpT, bp, nullptr, nullptr, nullptr, nullptr, out);
}

// Round 5
// 139.134 us; speedup vs baseline: 1.0416x; 1.0416x over previous
//
#include <hip/hip_runtime.h>
#include <stdint.h>

// Problem constants
#define B_SZ 8
#define T_SZ 1024
#define DM   768
#define NH   12
#define DH   64
#define NTOK (B_SZ * T_SZ)   // 8192
#define NOUT (NTOK * DM)     // 6291456
#define INF  __builtin_inff()

typedef unsigned short u16;
typedef __attribute__((ext_vector_type(8))) short short8;   // 8 bf16 (4 VGPRs) MFMA frag
typedef __attribute__((ext_vector_type(4))) short short4v;
typedef __attribute__((ext_vector_type(4))) float f32x4;

#define MFMA16x16x32 __builtin_amdgcn_mfma_f32_16x16x32_bf16

__device__ __forceinline__ u16 f2bf(float f) {
    unsigned u = __builtin_bit_cast(unsigned, f);
    u += 0x7fffu + ((u >> 16) & 1u);   // RNE
    return (u16)(u >> 16);
}

__device__ __forceinline__ f32x4 max4(f32x4 a, f32x4 b) {
    f32x4 r; r.x = fmaxf(a.x, b.x); r.y = fmaxf(a.y, b.y);
    r.z = fmaxf(a.z, b.z); r.w = fmaxf(a.w, b.w); return r;
}
__device__ __forceinline__ f32x4 add4(f32x4 a, f32x4 b) {
    f32x4 r; r.x = a.x + b.x; r.y = a.y + b.y;
    r.z = a.z + b.z; r.w = a.w + b.w; return r;
}

// CK-proven pattern: integer-cast to AS1/AS3 pointers for the direct-to-LDS load.
__device__ __forceinline__ void gload16(const void* g, void* l) {
    __builtin_amdgcn_global_load_lds(
        (const __attribute__((address_space(1))) unsigned int*)(unsigned long long)(uintptr_t)g,
        (__attribute__((address_space(3))) unsigned int*)(unsigned int)(uintptr_t)l,
        16, 0, 0);
}

// ---------------- fp32 -> bf16 elementwise ----------------
__global__ __launch_bounds__(256) void cvt_bf16_kernel(const float* __restrict__ in,
                                                       u16* __restrict__ out, int n) {
    int i = (blockIdx.x * 256 + threadIdx.x) * 4;
    if (i >= n) return;
    f32x4 v = *(const f32x4*)(in + i);
    short4v o;
    o.x = (short)f2bf(v.x); o.y = (short)f2bf(v.y);
    o.z = (short)f2bf(v.z); o.w = (short)f2bf(v.w);
    *(short4v*)(out + i) = o;
}

// ---------------- transpose fp32 [R][C] -> bf16 [C][R] ----------------
__global__ __launch_bounds__(256) void transpose_bf16_kernel(const float* __restrict__ in,
                                                             u16* __restrict__ out,
                                                             int R, int C) {
    __shared__ float tile[32][33];
    int tx = threadIdx.x & 31, ty = threadIdx.x >> 5;   // 32 x 8
    int c0 = blockIdx.x * 32, r0 = blockIdx.y * 32;
    for (int i = ty; i < 32; i += 8)
        tile[i][tx] = in[(size_t)(r0 + i) * C + c0 + tx];
    __syncthreads();
    for (int i = ty; i < 32; i += 8)
        out[(size_t)(c0 + i) * R + r0 + tx] = f2bf(tile[tx][i]);
}

// ---------------- bf16 GEMM, K=768, 128x128 tile, dbuf 2-phase ----------------
// A [M][768] bf16 row-major, BT [N][768] bf16 (B transposed).
// Natural blockIdx order: round-robin XCD dispatch already partitions the
// m-dimension per XCD (A 1.5 MB + B 3.4 MB per-XCD L2 sets) — measured 26 MB
// fetch vs 98 MB with a "contiguous chunk" swizzle (round-4 lesson).
// Double-buffered: STAGE(k+1) issues before compute(k); one barrier per K-step.
template <int EPI>
__global__ __launch_bounds__(256, 4) void gemm_k768_kernel(
    const u16* __restrict__ A, const u16* __restrict__ BT, const float* __restrict__ bias,
    u16* __restrict__ qbf, u16* __restrict__ kbf, u16* __restrict__ vtb,
    float* __restrict__ outK, float* __restrict__ outV, float* __restrict__ outP)
{
    __shared__ alignas(16) u16 As[2][128 * 32];   // 8 KB each
    __shared__ alignas(16) u16 Bs[2][128 * 32];
    const int t   = threadIdx.x;
    const int wid = t >> 6, l = t & 63;
    const int lr  = l & 15, g = l >> 4;
    const int m0  = blockIdx.x * 128, n0 = blockIdx.y * 128;
    const int wm  = (wid >> 1) * 64, wn = (wid & 1) * 64;

    // staging: thread t carries row srow (and srow+64), phys slot t&3,
    // logical chunk = (t&3) ^ (srow&3)   ((srow+64)&3 == srow&3)
    const int srow = t >> 2;
    const int sch  = (t & 3) ^ (srow & 3);
    const u16* ga0 = A  + (size_t)(m0 + srow) * 768 + sch * 8;
    const u16* ga1 = A  + (size_t)(m0 + 64 + srow) * 768 + sch * 8;
    const u16* gb0 = BT + (size_t)(n0 + srow) * 768 + sch * 8;
    const u16* gb1 = BT + (size_t)(n0 + 64 + srow) * 768 + sch * 8;

#define GSTAGE(buf, k0) do {                              \
        gload16(ga0 + (k0), As[buf] + t * 8);             \
        gload16(ga1 + (k0), As[buf] + 2048 + t * 8);      \
        gload16(gb0 + (k0), Bs[buf] + t * 8);             \
        gload16(gb1 + (k0), Bs[buf] + 2048 + t * 8);      \
    } while (0)

    // fragment read column offset (u16): logical chunk g at row lr
    const int fco = (g ^ (lr & 3)) * 8;

    f32x4 acc[4][4] = {};
    GSTAGE(0, 0);
    __syncthreads();
    int cur = 0;
    #pragma unroll 1
    for (int k0 = 32; k0 <= 768; k0 += 32) {
        if (k0 < 768) GSTAGE(cur ^ 1, k0);
        const u16* aB = As[cur];
        const u16* bB = Bs[cur];
        short8 af[4], bfr[4];
        #pragma unroll
        for (int i = 0; i < 4; ++i)
            af[i] = *(const short8*)(aB + (wm + i * 16 + lr) * 32 + fco);
        #pragma unroll
        for (int j = 0; j < 4; ++j)
            bfr[j] = *(const short8*)(bB + (wn + j * 16 + lr) * 32 + fco);
        __builtin_amdgcn_s_setprio(1);
        #pragma unroll
        for (int i = 0; i < 4; ++i)
            #pragma unroll
            for (int j = 0; j < 4; ++j)
                acc[i][j] = MFMA16x16x32(af[i], bfr[j], acc[i][j], 0, 0, 0);
        __builtin_amdgcn_s_setprio(0);
        __syncthreads();   // drains staged loads; all waves done with buf cur
        cur ^= 1;
    }
#undef GSTAGE

    // C/D layout: col = lane&15, row = (lane>>4)*4 + reg  [verified m89/m91]
    #pragma unroll
    for (int j = 0; j < 4; ++j) {
        const int n = n0 + wn + j * 16 + lr;
        const float bn = bias[n];
        if (EPI == 0) {
            const int which = n / 768;           // 0=Q,1=K,2=V (wave-uniform)
            const int hd = n - which * 768;
            const int h = hd >> 6, dd = hd & 63;
            #pragma unroll
            for (int i = 0; i < 4; ++i) {
                #pragma unroll
                for (int r = 0; r < 4; ++r) {
                    const int m = m0 + wm + i * 16 + g * 4 + r;
                    const int b = m >> 10, tt = m & 1023;
                    const int idx = ((b * 12 + h) * 1024 + tt) * 64 + dd;
                    const float v = acc[i][j][r] + bn;
                    if (which == 0) {
                        // fold 1/sqrt(64) and log2(e) so attn exp2 needs no mul
                        qbf[idx] = f2bf(v * (0.125f * 1.44269504f));
                    } else if (which == 1) {
                        outK[idx] = v; kbf[idx] = f2bf(v);
                    } else {
                        outV[idx] = v;
                        vtb[(b * 12 + h) * 65536 + dd * 1024 + tt] = f2bf(v);
                    }
                }
            }
        } else {
            #pragma unroll
            for (int i = 0; i < 4; ++i)
                #pragma unroll
                for (int r = 0; r < 4; ++r) {
                    const int m = m0 + wm + i * 16 + g * 4 + r;
                    outP[(size_t)m * 768 + n] = acc[i][j][r] + bn;
                }
        }
    }
}

// ---------------- causal flash attention, LDS-staged 2-phase pipeline ----------------
// grid (96, 8), 4 waves. Block y handles q-tiles y and 15-y (uniform 17 rounds).
// K/V tiles (64 kt x 64 d bf16, 8 KB each) double-buffered in LDS via
// global_load_lds with XOR chunk-swizzle (chunk ^= row&7) applied on the GLOBAL
// source and on the ds_read address (both-sides rule). Wave owns 16 q columns.
__global__ __launch_bounds__(256, 3) void attn_kernel(
    const u16* __restrict__ Qb, const u16* __restrict__ Kb,
    const u16* __restrict__ Vt, u16* __restrict__ Ob)
{
    __shared__ alignas(16) u16 Ks[2][4096];     // [64 kt][8 chunks of 8 u16], swizzled
    __shared__ alignas(16) u16 Vs[2][4096];     // [64 d ][8 chunks of 8 u16], swizzled
    __shared__ alignas(16) u16 Pl[4][16 * 72];  // per-wave P: 16 q x (64+8 pad) u16
    const int bh = blockIdx.x;
    const int t = threadIdx.x;
    const int wid = t >> 6, l = t & 63;
    const int c = l & 15, g = l >> 4;
    u16* P = Pl[wid];
    const u16* Kp = Kb + (size_t)bh * 65536;    // [T][64]
    const u16* Vp = Vt + (size_t)bh * 65536;    // [64][T]
    const int b = bh / 12, h = bh - (bh / 12) * 12;

    const int srow = t >> 3;
    const int sch  = (t & 7) ^ (srow & 7);
    const u16* Ksrc0 = Kp + (size_t)srow * 64 + sch * 8;
    const u16* Ksrc1 = Kp + (size_t)(srow + 32) * 64 + sch * 8;
    const u16* Vsrc0 = Vp + (size_t)srow * 1024 + sch * 8;
    const u16* Vsrc1 = Vp + (size_t)(srow + 32) * 1024 + sch * 8;

    // fragment read offsets (u16): row c (within 16-row subtile), logical chunk g / g+4
    const int fo0 = c * 64 + ((g ^ (c & 7)) * 8);
    const int fo1 = c * 64 + (((g + 4) ^ (c & 7)) * 8);

#define STAGE(buf, kt0) do {                                        \
        gload16(Ksrc0 + (size_t)(kt0) * 64, Ks[buf] + t * 8);       \
        gload16(Ksrc1 + (size_t)(kt0) * 64, Ks[buf] + 2048 + t * 8);\
        gload16(Vsrc0 + (kt0),              Vs[buf] + t * 8);       \
        gload16(Vsrc1 + (kt0),              Vs[buf] + 2048 + t * 8);\
    } while (0)

    #pragma unroll 1
    for (int pass = 0; pass < 2; ++pass) {
        const int tile = pass ? (15 - blockIdx.y) : blockIdx.y;
        const int qbase = tile * 64 + wid * 16;
        const int qg = qbase + c;                // this lane's q column
        const u16* Qp = Qb + ((size_t)bh * 1024 + qg) * 64 + g * 8;
        const short8 bq0 = *(const short8*)(Qp);
        const short8 bq1 = *(const short8*)(Qp + 32);

        f32x4 oacc[4] = {};
        float mrow = -INF, lpart = 0.f;
        const int nb = tile + 1;                 // 64-wide KV blocks

        STAGE(0, 0);
        __syncthreads();
        int cur = 0;

        #pragma unroll 1
        for (int kb = 0; kb < nb; ++kb) {
            if (kb + 1 < nb) STAGE(cur ^ 1, (kb + 1) << 6);
            const u16* kB = Ks[cur];
            const u16* vB = Vs[cur];
            short8 af0[4], af1[4], vf0[4], vf1[4];
            #pragma unroll
            for (int j = 0; j < 4; ++j) {
                af0[j] = *(const short8*)(kB + j * 1024 + fo0);
                af1[j] = *(const short8*)(kB + j * 1024 + fo1);
            }
            #pragma unroll
            for (int dt = 0; dt < 4; ++dt) {
                vf0[dt] = *(const short8*)(vB + dt * 1024 + fo0);
                vf1[dt] = *(const short8*)(vB + dt * 1024 + fo1);
            }
            // QK^T: D[kt][q], s[j] covers kt rows j*16 + g*4 + r
            f32x4 s[4] = {};
            __builtin_amdgcn_s_setprio(1);
            #pragma unroll
            for (int j = 0; j < 4; ++j) {
                s[j] = MFMA16x16x32(af0[j], bq0, s[j], 0, 0, 0);
                s[j] = MFMA16x16x32(af1[j], bq1, s[j], 0, 0, 0);
            }
            __builtin_amdgcn_s_setprio(0);
            if (kb == nb - 1) {                  // only diagonal block masks
                const int kt0 = kb << 6;
                #pragma unroll
                for (int j = 0; j < 4; ++j)
                    #pragma unroll
                    for (int r = 0; r < 4; ++r)
                        if (kt0 + j * 16 + g * 4 + r > qg) s[j][r] = -INF;
            }
            // softmax (scores already in log2 units); tree max
            f32x4 mm = max4(max4(s[0], s[1]), max4(s[2], s[3]));
            float tm = fmaxf(fmaxf(mm.x, mm.y), fmaxf(mm.z, mm.w));
            tm = fmaxf(tm, __shfl_xor(tm, 16));
            tm = fmaxf(tm, __shfl_xor(tm, 32));
            // defer-max (T13): skip rescale while growth <= 8 (log2 units; P <= 256)
            const bool keep = (__all(tm <= mrow + 8.f) != 0);
            const float mnew = keep ? mrow : fmaxf(mrow, tm);
            if (!keep) {
                const float sc = exp2f(mrow - mnew);
                mrow = mnew;
                lpart *= sc;
                #pragma unroll
                for (int dt = 0; dt < 4; ++dt) {
                    oacc[dt][0] *= sc; oacc[dt][1] *= sc;
                    oacc[dt][2] *= sc; oacc[dt][3] *= sc;
                }
            }
            f32x4 p[4];
            #pragma unroll
            for (int j = 0; j < 4; ++j) {
                p[j].x = exp2f(s[j].x - mnew); p[j].y = exp2f(s[j].y - mnew);
                p[j].z = exp2f(s[j].z - mnew); p[j].w = exp2f(s[j].w - mnew);
            }
            f32x4 ps = add4(add4(p[0], p[1]), add4(p[2], p[3]));
            lpart += (ps.x + ps.y) + (ps.z + ps.w);   // per-lane partial (g-reduce deferred)
            // P[q=c][kt] bf16 -> LDS (row stride 72 u16 = 144 B, 2-way conflicts only)
            #pragma unroll
            for (int j = 0; j < 4; ++j) {
                short4v w;
                w.x = (short)f2bf(p[j].x); w.y = (short)f2bf(p[j].y);
                w.z = (short)f2bf(p[j].z); w.w = (short)f2bf(p[j].w);
                *(short4v*)(P + c * 72 + j * 16 + g * 4) = w;
            }
            const short8 pf0 = *(const short8*)(P + c * 72 + g * 8);
            const short8 pf1 = *(const short8*)(P + c * 72 + 32 + g * 8);
            // PV: A = V^T rows (d), B = P^T -> D[d][q]
            __builtin_amdgcn_s_setprio(1);
            #pragma unroll
            for (int dt = 0; dt < 4; ++dt) {
                oacc[dt] = MFMA16x16x32(vf0[dt], pf0, oacc[dt], 0, 0, 0);
                oacc[dt] = MFMA16x16x32(vf1[dt], pf1, oacc[dt], 0, 0, 0);
            }
            __builtin_amdgcn_s_setprio(0);
            __syncthreads();   // drains staging (vmcnt 0) + all waves done with buf cur
            cur ^= 1;
        }
        float lsum = lpart;
        lsum += __shfl_xor(lsum, 16);
        lsum += __shfl_xor(lsum, 32);
        const float li = 1.f / lsum;             // lane-local (col=q layout)
        #pragma unroll
        for (int dt = 0; dt < 4; ++dt) {
            short4v o;
            o.x = (short)f2bf(oacc[dt][0] * li);
            o.y = (short)f2bf(oacc[dt][1] * li);
            o.z = (short)f2bf(oacc[dt][2] * li);
            o.w = (short)f2bf(oacc[dt][3] * li);
            *(short4v*)(Ob + (size_t)(b * 1024 + qg) * 768 + h * 64 + dt * 16 + g * 4) = o;
        }
    }
#undef STAGE
}

extern "C" void kernel_launch(void* const* d_in, const int* in_sizes, int n_in,
                              void* d_out, int out_size, void* d_ws, size_t ws_size,
                              hipStream_t stream) {
    const float* hs = (const float*)d_in[0];   // [8,1024,768]
    const float* Wa = (const float*)d_in[1];   // [768,2304]
    const float* ba = (const float*)d_in[2];   // [2304]
    const float* Wp = (const float*)d_in[3];   // [768,768]
    const float* bp = (const float*)d_in[4];   // [768]
    float* out = (float*)d_out;                // out | K | V  (each NOUT fp32)

    u16* ws  = (u16*)d_ws;
    u16* Xbf = ws;                             // [8192][768]
    u16* WaT = Xbf + NOUT;                     // [2304][768]
    u16* WpT = WaT + 768 * 2304;               // [768][768]
    u16* Qbf = WpT + 768 * 768;                // [B,H,T,64] (pre-scaled by 0.125*log2e)
    u16* Kbf = Qbf + NOUT;                     // [B,H,T,64]
    u16* VTb = Kbf + NOUT;                     // [B,H,64,T]
    u16* Obf = VTb + NOUT;                     // [8192][768]

    cvt_bf16_kernel<<<NOUT / 1024, 256, 0, stream>>>(hs, Xbf, NOUT);
    transpose_bf16_kernel<<<dim3(2304 / 32, 768 / 32), 256, 0, stream>>>(Wa, WaT, 768, 2304);
    transpose_bf16_kernel<<<dim3(768 / 32, 768 / 32), 256, 0, stream>>>(Wp, WpT, 768, 768);
    gemm_k768_kernel<0><<<dim3(64, 18), 256, 0, stream>>>(
        Xbf, WaT, ba, Qbf, Kbf, VTb, out + NOUT, out + 2 * (size_t)NOUT, nullptr);
    attn_kernel<<<dim3(96, 8), 256, 0, stream>>>(Qbf, Kbf, VTb, Obf);
    gemm_k768_kernel<1><<<dim3(64, 6), 256, 0, stream>>>(
        Obf, WpT, bp, nullptr, nullptr, nullptr, nullptr, nullptr, out);
}

// Round 6
// 133.447 us; speedup vs baseline: 1.0860x; 1.0426x over previous
//
#include <hip/hip_runtime.h>
#include <stdint.h>

// Problem constants
#define B_SZ 8
#define T_SZ 1024
#define DM   768
#define NH   12
#define DH   64
#define NTOK (B_SZ * T_SZ)   // 8192
#define NOUT (NTOK * DM)     // 6291456
#define INF  __builtin_inff()

typedef unsigned short u16;
typedef __attribute__((ext_vector_type(8))) short short8;   // 8 bf16 (4 VGPRs) MFMA frag
typedef __attribute__((ext_vector_type(4))) short short4v;
typedef __attribute__((ext_vector_type(4))) float f32x4;

#define MFMA16x16x32 __builtin_amdgcn_mfma_f32_16x16x32_bf16

__device__ __forceinline__ u16 f2bf(float f) {
    unsigned u = __builtin_bit_cast(unsigned, f);
    u += 0x7fffu + ((u >> 16) & 1u);   // RNE
    return (u16)(u >> 16);
}

__device__ __forceinline__ f32x4 max4(f32x4 a, f32x4 b) {
    f32x4 r; r.x = fmaxf(a.x, b.x); r.y = fmaxf(a.y, b.y);
    r.z = fmaxf(a.z, b.z); r.w = fmaxf(a.w, b.w); return r;
}
__device__ __forceinline__ f32x4 add4(f32x4 a, f32x4 b) {
    f32x4 r; r.x = a.x + b.x; r.y = a.y + b.y;
    r.z = a.z + b.z; r.w = a.w + b.w; return r;
}

// CK-proven pattern: integer-cast to AS1/AS3 pointers for the direct-to-LDS load.
__device__ __forceinline__ void gload16(const void* g, void* l) {
    __builtin_amdgcn_global_load_lds(
        (const __attribute__((address_space(1))) unsigned int*)(unsigned long long)(uintptr_t)g,
        (__attribute__((address_space(3))) unsigned int*)(unsigned int)(uintptr_t)l,
        16, 0, 0);
}

// ---------------- fp32 -> bf16 elementwise ----------------
__global__ __launch_bounds__(256) void cvt_bf16_kernel(const float* __restrict__ in,
                                                       u16* __restrict__ out, int n) {
    int i = (blockIdx.x * 256 + threadIdx.x) * 4;
    if (i >= n) return;
    f32x4 v = *(const f32x4*)(in + i);
    short4v o;
    o.x = (short)f2bf(v.x); o.y = (short)f2bf(v.y);
    o.z = (short)f2bf(v.z); o.w = (short)f2bf(v.w);
    *(short4v*)(out + i) = o;
}

// ---------------- transpose fp32 [R][C] -> bf16 [C][R] ----------------
__global__ __launch_bounds__(256) void transpose_bf16_kernel(const float* __restrict__ in,
                                                             u16* __restrict__ out,
                                                             int R, int C) {
    __shared__ float tile[32][33];
    int tx = threadIdx.x & 31, ty = threadIdx.x >> 5;   // 32 x 8
    int c0 = blockIdx.x * 32, r0 = blockIdx.y * 32;
    for (int i = ty; i < 32; i += 8)
        tile[i][tx] = in[(size_t)(r0 + i) * C + c0 + tx];
    __syncthreads();
    for (int i = ty; i < 32; i += 8)
        out[(size_t)(c0 + i) * R + r0 + tx] = f2bf(tile[tx][i]);
}

// ---------------- per-head V transpose: fp32 [96][1024][64] -> bf16 [96][64][1024] ----------------
// Separate kernel, reads L2-hot V fp32. Measured ~6 us in round 4 — cheaper than
// the 2-B-scatter epilogue inside the GEMM (~10-18 us, round-5 lesson).
__global__ __launch_bounds__(256) void transpose_v_kernel(const float* __restrict__ in,
                                                          u16* __restrict__ out) {
    __shared__ float tile[32][33];
    const int head = blockIdx.z;
    const int t0 = blockIdx.x * 32, d0 = blockIdx.y * 32;
    const float* ip = in + (size_t)head * 65536;
    u16* op = out + (size_t)head * 65536;
    int tx = threadIdx.x & 31, ty = threadIdx.x >> 5;
    for (int i = ty; i < 32; i += 8)
        tile[i][tx] = ip[(size_t)(t0 + i) * 64 + d0 + tx];
    __syncthreads();
    for (int i = ty; i < 32; i += 8)
        op[(size_t)(d0 + i) * 1024 + t0 + tx] = f2bf(tile[tx][i]);
}

// ---------------- bf16 GEMM, K=768, 128x128 tile, dbuf 2-phase ----------------
// A [M][768] bf16 row-major, BT [N][768] bf16 (B transposed).
// Natural blockIdx order: round-robin XCD dispatch already partitions the
// m-dimension per XCD (x == xcd mod 8 for every y-stripe -> A 1.5 MB + B 3.4 MB
// per-XCD L2 set; measured 26-29 MB fetch vs 98 MB with a contiguous-chunk
// swizzle, round-4 lesson). Double-buffered: STAGE(k+1) before compute(k).
template <int EPI>
__global__ __launch_bounds__(256, 4) void gemm_k768_kernel(
    const u16* __restrict__ A, const u16* __restrict__ BT, const float* __restrict__ bias,
    u16* __restrict__ qbf, u16* __restrict__ kbf,
    float* __restrict__ outK, float* __restrict__ outV, float* __restrict__ outP)
{
    __shared__ alignas(16) u16 As[2][128 * 32];   // 8 KB each
    __shared__ alignas(16) u16 Bs[2][128 * 32];
    const int t   = threadIdx.x;
    const int wid = t >> 6, l = t & 63;
    const int lr  = l & 15, g = l >> 4;
    const int m0  = blockIdx.x * 128, n0 = blockIdx.y * 128;
    const int wm  = (wid >> 1) * 64, wn = (wid & 1) * 64;

    // staging: thread t carries row srow (and srow+64), phys slot t&3,
    // logical chunk = (t&3) ^ (srow&3)   ((srow+64)&3 == srow&3)
    const int srow = t >> 2;
    const int sch  = (t & 3) ^ (srow & 3);
    const u16* ga0 = A  + (size_t)(m0 + srow) * 768 + sch * 8;
    const u16* ga1 = A  + (size_t)(m0 + 64 + srow) * 768 + sch * 8;
    const u16* gb0 = BT + (size_t)(n0 + srow) * 768 + sch * 8;
    const u16* gb1 = BT + (size_t)(n0 + 64 + srow) * 768 + sch * 8;

#define GSTAGE(buf, k0) do {                              \
        gload16(ga0 + (k0), As[buf] + t * 8);             \
        gload16(ga1 + (k0), As[buf] + 2048 + t * 8);      \
        gload16(gb0 + (k0), Bs[buf] + t * 8);             \
        gload16(gb1 + (k0), Bs[buf] + 2048 + t * 8);      \
    } while (0)

    // fragment read column offset (u16): logical chunk g at row lr
    const int fco = (g ^ (lr & 3)) * 8;

    f32x4 acc[4][4] = {};
    GSTAGE(0, 0);
    __syncthreads();
    int cur = 0;
    #pragma unroll 1
    for (int k0 = 32; k0 <= 768; k0 += 32) {
        if (k0 < 768) GSTAGE(cur ^ 1, k0);
        const u16* aB = As[cur];
        const u16* bB = Bs[cur];
        short8 af[4], bfr[4];
        #pragma unroll
        for (int i = 0; i < 4; ++i)
            af[i] = *(const short8*)(aB + (wm + i * 16 + lr) * 32 + fco);
        #pragma unroll
        for (int j = 0; j < 4; ++j)
            bfr[j] = *(const short8*)(bB + (wn + j * 16 + lr) * 32 + fco);
        __builtin_amdgcn_s_setprio(1);
        #pragma unroll
        for (int i = 0; i < 4; ++i)
            #pragma unroll
            for (int j = 0; j < 4; ++j)
                acc[i][j] = MFMA16x16x32(af[i], bfr[j], acc[i][j], 0, 0, 0);
        __builtin_amdgcn_s_setprio(0);
        __syncthreads();   // drains staged loads; all waves done with buf cur
        cur ^= 1;
    }
#undef GSTAGE

    // C/D layout: col = lane&15, row = (lane>>4)*4 + reg  [verified m89/m91]
    #pragma unroll
    for (int j = 0; j < 4; ++j) {
        const int n = n0 + wn + j * 16 + lr;
        const float bn = bias[n];
        if (EPI == 0) {
            const int which = n / 768;           // 0=Q,1=K,2=V (wave-uniform)
            const int hd = n - which * 768;
            const int h = hd >> 6, dd = hd & 63;
            #pragma unroll
            for (int i = 0; i < 4; ++i) {
                #pragma unroll
                for (int r = 0; r < 4; ++r) {
                    const int m = m0 + wm + i * 16 + g * 4 + r;
                    const int b = m >> 10, tt = m & 1023;
                    const int idx = ((b * 12 + h) * 1024 + tt) * 64 + dd;
                    const float v = acc[i][j][r] + bn;
                    if (which == 0) {
                        // fold 1/sqrt(64) and log2(e) so attn exp2 needs no mul
                        qbf[idx] = f2bf(v * (0.125f * 1.44269504f));
                    } else if (which == 1) {
                        outK[idx] = v; kbf[idx] = f2bf(v);
                    } else {
                        outV[idx] = v;   // V^T bf16 produced by transpose_v_kernel
                    }
                }
            }
        } else {
            #pragma unroll
            for (int i = 0; i < 4; ++i)
                #pragma unroll
                for (int r = 0; r < 4; ++r) {
                    const int m = m0 + wm + i * 16 + g * 4 + r;
                    outP[(size_t)m * 768 + n] = acc[i][j][r] + bn;
                }
        }
    }
}

// ---------------- causal flash attention, LDS-staged 2-phase pipeline ----------------
// grid (96, 8), 4 waves. Block y handles q-tiles y and 15-y (uniform 17 rounds).
// K/V tiles (64 kt x 64 d bf16, 8 KB each) double-buffered in LDS via
// global_load_lds with XOR chunk-swizzle (chunk ^= row&7) applied on the GLOBAL
// source and on the ds_read address (both-sides rule). Wave owns 16 q columns.
__global__ __launch_bounds__(256, 3) void attn_kernel(
    const u16* __restrict__ Qb, const u16* __restrict__ Kb,
    const u16* __restrict__ Vt, u16* __restrict__ Ob)
{
    __shared__ alignas(16) u16 Ks[2][4096];     // [64 kt][8 chunks of 8 u16], swizzled
    __shared__ alignas(16) u16 Vs[2][4096];     // [64 d ][8 chunks of 8 u16], swizzled
    __shared__ alignas(16) u16 Pl[4][16 * 72];  // per-wave P: 16 q x (64+8 pad) u16
    const int bh = blockIdx.x;
    const int t = threadIdx.x;
    const int wid = t >> 6, l = t & 63;
    const int c = l & 15, g = l >> 4;
    u16* P = Pl[wid];
    const u16* Kp = Kb + (size_t)bh * 65536;    // [T][64]
    const u16* Vp = Vt + (size_t)bh * 65536;    // [64][T]
    const int b = bh / 12, h = bh - (bh / 12) * 12;

    const int srow = t >> 3;
    const int sch  = (t & 7) ^ (srow & 7);
    const u16* Ksrc0 = Kp + (size_t)srow * 64 + sch * 8;
    const u16* Ksrc1 = Kp + (size_t)(srow + 32) * 64 + sch * 8;
    const u16* Vsrc0 = Vp + (size_t)srow * 1024 + sch * 8;
    const u16* Vsrc1 = Vp + (size_t)(srow + 32) * 1024 + sch * 8;

    // fragment read offsets (u16): row c (within 16-row subtile), logical chunk g / g+4
    const int fo0 = c * 64 + ((g ^ (c & 7)) * 8);
    const int fo1 = c * 64 + (((g + 4) ^ (c & 7)) * 8);

#define STAGE(buf, kt0) do {                                        \
        gload16(Ksrc0 + (size_t)(kt0) * 64, Ks[buf] + t * 8);       \
        gload16(Ksrc1 + (size_t)(kt0) * 64, Ks[buf] + 2048 + t * 8);\
        gload16(Vsrc0 + (kt0),              Vs[buf] + t * 8);       \
        gload16(Vsrc1 + (kt0),              Vs[buf] + 2048 + t * 8);\
    } while (0)

    #pragma unroll 1
    for (int pass = 0; pass < 2; ++pass) {
        const int tile = pass ? (15 - blockIdx.y) : blockIdx.y;
        const int qbase = tile * 64 + wid * 16;
        const int qg = qbase + c;                // this lane's q column
        const u16* Qp = Qb + ((size_t)bh * 1024 + qg) * 64 + g * 8;
        const short8 bq0 = *(const short8*)(Qp);
        const short8 bq1 = *(const short8*)(Qp + 32);

        f32x4 oacc[4] = {};
        float mrow = -INF, lpart = 0.f;
        const int nb = tile + 1;                 // 64-wide KV blocks

        STAGE(0, 0);
        __syncthreads();
        int cur = 0;

        #pragma unroll 1
        for (int kb = 0; kb < nb; ++kb) {
            if (kb + 1 < nb) STAGE(cur ^ 1, (kb + 1) << 6);
            const u16* kB = Ks[cur];
            const u16* vB = Vs[cur];
            short8 af0[4], af1[4], vf0[4], vf1[4];
            #pragma unroll
            for (int j = 0; j < 4; ++j) {
                af0[j] = *(const short8*)(kB + j * 1024 + fo0);
                af1[j] = *(const short8*)(kB + j * 1024 + fo1);
            }
            #pragma unroll
            for (int dt = 0; dt < 4; ++dt) {
                vf0[dt] = *(const short8*)(vB + dt * 1024 + fo0);
                vf1[dt] = *(const short8*)(vB + dt * 1024 + fo1);
            }
            // QK^T: D[kt][q], s[j] covers kt rows j*16 + g*4 + r
            f32x4 s[4] = {};
            __builtin_amdgcn_s_setprio(1);
            #pragma unroll
            for (int j = 0; j < 4; ++j) {
                s[j] = MFMA16x16x32(af0[j], bq0, s[j], 0, 0, 0);
                s[j] = MFMA16x16x32(af1[j], bq1, s[j], 0, 0, 0);
            }
            __builtin_amdgcn_s_setprio(0);
            if (kb == nb - 1) {                  // only diagonal block masks
                const int kt0 = kb << 6;
                #pragma unroll
                for (int j = 0; j < 4; ++j)
                    #pragma unroll
                    for (int r = 0; r < 4; ++r)
                        if (kt0 + j * 16 + g * 4 + r > qg) s[j][r] = -INF;
            }
            // softmax (scores already in log2 units); tree max
            f32x4 mm = max4(max4(s[0], s[1]), max4(s[2], s[3]));
            float tm = fmaxf(fmaxf(mm.x, mm.y), fmaxf(mm.z, mm.w));
            tm = fmaxf(tm, __shfl_xor(tm, 16));
            tm = fmaxf(tm, __shfl_xor(tm, 32));
            // defer-max (T13): skip rescale while growth <= 8 (log2 units; P <= 256)
            const bool keep = (__all(tm <= mrow + 8.f) != 0);
            const float mnew = keep ? mrow : fmaxf(mrow, tm);
            if (!keep) {
                const float sc = exp2f(mrow - mnew);
                mrow = mnew;
                lpart *= sc;
                #pragma unroll
                for (int dt = 0; dt < 4; ++dt) {
                    oacc[dt][0] *= sc; oacc[dt][1] *= sc;
                    oacc[dt][2] *= sc; oacc[dt][3] *= sc;
                }
            }
            f32x4 p[4];
            #pragma unroll
            for (int j = 0; j < 4; ++j) {
                p[j].x = exp2f(s[j].x - mnew); p[j].y = exp2f(s[j].y - mnew);
                p[j].z = exp2f(s[j].z - mnew); p[j].w = exp2f(s[j].w - mnew);
            }
            f32x4 ps = add4(add4(p[0], p[1]), add4(p[2], p[3]));
            lpart += (ps.x + ps.y) + (ps.z + ps.w);   // per-lane partial (g-reduce deferred)
            // P[q=c][kt] bf16 -> LDS (row stride 72 u16 = 144 B, 2-way conflicts only)
            #pragma unroll
            for (int j = 0; j < 4; ++j) {
                short4v w;
                w.x = (short)f2bf(p[j].x); w.y = (short)f2bf(p[j].y);
                w.z = (short)f2bf(p[j].z); w.w = (short)f2bf(p[j].w);
                *(short4v*)(P + c * 72 + j * 16 + g * 4) = w;
            }
            const short8 pf0 = *(const short8*)(P + c * 72 + g * 8);
            const short8 pf1 = *(const short8*)(P + c * 72 + 32 + g * 8);
            // PV: A = V^T rows (d), B = P^T -> D[d][q]
            __builtin_amdgcn_s_setprio(1);
            #pragma unroll
            for (int dt = 0; dt < 4; ++dt) {
                oacc[dt] = MFMA16x16x32(vf0[dt], pf0, oacc[dt], 0, 0, 0);
                oacc[dt] = MFMA16x16x32(vf1[dt], pf1, oacc[dt], 0, 0, 0);
            }
            __builtin_amdgcn_s_setprio(0);
            __syncthreads();   // drains staging (vmcnt 0) + all waves done with buf cur
            cur ^= 1;
        }
        float lsum = lpart;
        lsum += __shfl_xor(lsum, 16);
        lsum += __shfl_xor(lsum, 32);
        const float li = 1.f / lsum;             // lane-local (col=q layout)
        #pragma unroll
        for (int dt = 0; dt < 4; ++dt) {
            short4v o;
            o.x = (short)f2bf(oacc[dt][0] * li);
            o.y = (short)f2bf(oacc[dt][1] * li);
            o.z = (short)f2bf(oacc[dt][2] * li);
            o.w = (short)f2bf(oacc[dt][3] * li);
            *(short4v*)(Ob + (size_t)(b * 1024 + qg) * 768 + h * 64 + dt * 16 + g * 4) = o;
        }
    }
#undef STAGE
}

extern "C" void kernel_launch(void* const* d_in, const int* in_sizes, int n_in,
                              void* d_out, int out_size, void* d_ws, size_t ws_size,
                              hipStream_t stream) {
    const float* hs = (const float*)d_in[0];   // [8,1024,768]
    const float* Wa = (const float*)d_in[1];   // [768,2304]
    const float* ba = (const float*)d_in[2];   // [2304]
    const float* Wp = (const float*)d_in[3];   // [768,768]
    const float* bp = (const float*)d_in[4];   // [768]
    float* out = (float*)d_out;                // out | K | V  (each NOUT fp32)

    u16* ws  = (u16*)d_ws;
    u16* Xbf = ws;                             // [8192][768]
    u16* WaT = Xbf + NOUT;                     // [2304][768]
    u16* WpT = WaT + 768 * 2304;               // [768][768]
    u16* Qbf = WpT + 768 * 768;                // [B,H,T,64] (pre-scaled by 0.125*log2e)
    u16* Kbf = Qbf + NOUT;                     // [B,H,T,64]
    u16* VTb = Kbf + NOUT;                     // [B,H,64,T]
    u16* Obf = VTb + NOUT;                     // [8192][768]

    cvt_bf16_kernel<<<NOUT / 1024, 256, 0, stream>>>(hs, Xbf, NOUT);
    transpose_bf16_kernel<<<dim3(2304 / 32, 768 / 32), 256, 0, stream>>>(Wa, WaT, 768, 2304);
    transpose_bf16_kernel<<<dim3(768 / 32, 768 / 32), 256, 0, stream>>>(Wp, WpT, 768, 768);
    gemm_k768_kernel<0><<<dim3(64, 18), 256, 0, stream>>>(
        Xbf, WaT, ba, Qbf, Kbf, out + NOUT, out + 2 * (size_t)NOUT, nullptr);
    transpose_v_kernel<<<dim3(32, 2, 96), 256, 0, stream>>>(out + 2 * (size_t)NOUT, VTb);
    attn_kernel<<<dim3(96, 8), 256, 0, stream>>>(Qbf, Kbf, VTb, Obf);
    gemm_k768_kernel<1><<<dim3(64, 6), 256, 0, stream>>>(
        Obf, WpT, bp, nullptr, nullptr, nullptr, nullptr, out);
}

// Round 7
// 130.645 us; speedup vs baseline: 1.1093x; 1.0214x over previous
//
#include <hip/hip_runtime.h>
#include <stdint.h>

// Problem constants
#define B_SZ 8
#define T_SZ 1024
#define DM   768
#define NH   12
#define DH   64
#define NTOK (B_SZ * T_SZ)   // 8192
#define NOUT (NTOK * DM)     // 6291456
#define INF  __builtin_inff()

typedef unsigned short u16;
typedef __attribute__((ext_vector_type(8))) short short8;   // 8 bf16 (4 VGPRs) MFMA frag
typedef __attribute__((ext_vector_type(4))) short short4v;
typedef __attribute__((ext_vector_type(4))) float f32x4;

#define MFMA16x16x32 __builtin_amdgcn_mfma_f32_16x16x32_bf16

__device__ __forceinline__ u16 f2bf(float f) {
    unsigned u = __builtin_bit_cast(unsigned, f);
    u += 0x7fffu + ((u >> 16) & 1u);   // RNE
    return (u16)(u >> 16);
}

__device__ __forceinline__ f32x4 max4(f32x4 a, f32x4 b) {
    f32x4 r; r.x = fmaxf(a.x, b.x); r.y = fmaxf(a.y, b.y);
    r.z = fmaxf(a.z, b.z); r.w = fmaxf(a.w, b.w); return r;
}
__device__ __forceinline__ f32x4 add4(f32x4 a, f32x4 b) {
    f32x4 r; r.x = a.x + b.x; r.y = a.y + b.y;
    r.z = a.z + b.z; r.w = a.w + b.w; return r;
}

// CK-proven pattern: integer-cast to AS1/AS3 pointers for the direct-to-LDS load.
__device__ __forceinline__ void gload16(const void* g, void* l) {
    __builtin_amdgcn_global_load_lds(
        (const __attribute__((address_space(1))) unsigned int*)(unsigned long long)(uintptr_t)g,
        (__attribute__((address_space(3))) unsigned int*)(unsigned int)(uintptr_t)l,
        16, 0, 0);
}

// ---------------- fp32 -> bf16 elementwise ----------------
__global__ __launch_bounds__(256) void cvt_bf16_kernel(const float* __restrict__ in,
                                                       u16* __restrict__ out, int n) {
    int i = (blockIdx.x * 256 + threadIdx.x) * 4;
    if (i >= n) return;
    f32x4 v = *(const f32x4*)(in + i);
    short4v o;
    o.x = (short)f2bf(v.x); o.y = (short)f2bf(v.y);
    o.z = (short)f2bf(v.z); o.w = (short)f2bf(v.w);
    *(short4v*)(out + i) = o;
}

// ---------------- transpose fp32 [R][C] -> bf16 [C][R] ----------------
__global__ __launch_bounds__(256) void transpose_bf16_kernel(const float* __restrict__ in,
                                                             u16* __restrict__ out,
                                                             int R, int C) {
    __shared__ float tile[32][33];
    int tx = threadIdx.x & 31, ty = threadIdx.x >> 5;   // 32 x 8
    int c0 = blockIdx.x * 32, r0 = blockIdx.y * 32;
    for (int i = ty; i < 32; i += 8)
        tile[i][tx] = in[(size_t)(r0 + i) * C + c0 + tx];
    __syncthreads();
    for (int i = ty; i < 32; i += 8)
        out[(size_t)(c0 + i) * R + r0 + tx] = f2bf(tile[tx][i]);
}

// ---------------- per-head V transpose: fp32 [96][1024][64] -> bf16 [96][64][1024] ----------------
__global__ __launch_bounds__(256) void transpose_v_kernel(const float* __restrict__ in,
                                                          u16* __restrict__ out) {
    __shared__ float tile[32][33];
    const int head = blockIdx.z;
    const int t0 = blockIdx.x * 32, d0 = blockIdx.y * 32;
    const float* ip = in + (size_t)head * 65536;
    u16* op = out + (size_t)head * 65536;
    int tx = threadIdx.x & 31, ty = threadIdx.x >> 5;
    for (int i = ty; i < 32; i += 8)
        tile[i][tx] = ip[(size_t)(t0 + i) * 64 + d0 + tx];
    __syncthreads();
    for (int i = ty; i < 32; i += 8)
        op[(size_t)(d0 + i) * 1024 + t0 + tx] = f2bf(tile[tx][i]);
}

// ---------------- bf16 GEMM, K=768, 128x128 tile, 4-deep pipeline + counted vmcnt ----------------
// A [M][768] bf16 row-major, BT [N][768] bf16 (B transposed).
// 4 LDS buffers (BK=32, 8 KB/operand/buf = 64 KB): tile kt+3 is staged during
// iteration kt -> 2 full tiles (8 loads/thread) always in flight; per-iteration
// wait is s_waitcnt vmcnt(8), NEVER 0 until the tail (T4). Raw s_barrier (no
// compiler vmcnt(0) drain). Swizzle: phys_chunk = chunk ^ ((row>>1)&3) makes
// the 16-lane b128 reads 2-way (free); applied to global SOURCE and ds_read.
template <int EPI>
__global__ __launch_bounds__(256, 2) void gemm_k768_kernel(
    const u16* __restrict__ A, const u16* __restrict__ BT, const float* __restrict__ bias,
    u16* __restrict__ qbf, u16* __restrict__ kbf,
    float* __restrict__ outK, float* __restrict__ outV, float* __restrict__ outP)
{
    __shared__ alignas(16) u16 As[4][128 * 32];   // 8 KB each
    __shared__ alignas(16) u16 Bs[4][128 * 32];
    const int t   = threadIdx.x;
    const int wid = t >> 6, l = t & 63;
    const int lr  = l & 15, g = l >> 4;
    const int m0  = blockIdx.x * 128, n0 = blockIdx.y * 128;
    const int wm  = (wid >> 1) * 64, wn = (wid & 1) * 64;

    // staging: thread t carries rows srow and srow+64, phys slot t&3,
    // logical chunk = (t&3) ^ ((srow>>1)&3)   (same for srow+64: 64/2 % 4 == 0)
    const int srow = t >> 2;
    const int sch  = ((t & 3) ^ ((srow >> 1) & 3)) * 8;
    const u16* ga0 = A  + (size_t)(m0 + srow) * 768 + sch;
    const u16* ga1 = A  + (size_t)(m0 + 64 + srow) * 768 + sch;
    const u16* gb0 = BT + (size_t)(n0 + srow) * 768 + sch;
    const u16* gb1 = BT + (size_t)(n0 + 64 + srow) * 768 + sch;

#define GSTAGE(buf, kt) do {                              \
        gload16(ga0 + (kt) * 32, As[buf] + t * 8);        \
        gload16(ga1 + (kt) * 32, As[buf] + 2048 + t * 8); \
        gload16(gb0 + (kt) * 32, Bs[buf] + t * 8);        \
        gload16(gb1 + (kt) * 32, Bs[buf] + 2048 + t * 8); \
    } while (0)

    // fragment read chunk offset (u16): logical chunk g at row (..+lr)
    const int fco = (g ^ ((lr >> 1) & 3)) * 8;

    f32x4 acc[4][4] = {};
    GSTAGE(0, 0); GSTAGE(1, 1); GSTAGE(2, 2);             // 12 loads in flight
    asm volatile("s_waitcnt vmcnt(8)" ::: "memory");      // tile 0 landed
    __builtin_amdgcn_s_barrier();
    __builtin_amdgcn_sched_barrier(0);

    #pragma unroll 1
    for (int kt = 0; kt < 24; ++kt) {
        const int buf = kt & 3;
        if (kt < 21) GSTAGE((kt + 3) & 3, kt + 3);        // keep 2 tiles ahead
        const u16* aB = As[buf];
        const u16* bB = Bs[buf];
        short8 af[4], bfr[4];
        #pragma unroll
        for (int i = 0; i < 4; ++i)
            af[i] = *(const short8*)(aB + (wm + i * 16 + lr) * 32 + fco);
        #pragma unroll
        for (int j = 0; j < 4; ++j)
            bfr[j] = *(const short8*)(bB + (wn + j * 16 + lr) * 32 + fco);
        __builtin_amdgcn_s_setprio(1);
        #pragma unroll
        for (int i = 0; i < 4; ++i)
            #pragma unroll
            for (int j = 0; j < 4; ++j)
                acc[i][j] = MFMA16x16x32(af[i], bfr[j], acc[i][j], 0, 0, 0);
        __builtin_amdgcn_s_setprio(0);
        // counted waits: next iteration's buffer must be landed in LDS before
        // the barrier publishes it; keep the 2 newest tiles in flight.
        if (kt < 21)       asm volatile("s_waitcnt vmcnt(8)" ::: "memory");
        else if (kt == 21) asm volatile("s_waitcnt vmcnt(4)" ::: "memory");
        else if (kt == 22) asm volatile("s_waitcnt vmcnt(0)" ::: "memory");
        __builtin_amdgcn_s_barrier();
        __builtin_amdgcn_sched_barrier(0);
    }
#undef GSTAGE

    // C/D layout: col = lane&15, row = (lane>>4)*4 + reg  [verified m89/m91]
    #pragma unroll
    for (int j = 0; j < 4; ++j) {
        const int n = n0 + wn + j * 16 + lr;
        const float bn = bias[n];
        if (EPI == 0) {
            const int which = n / 768;           // 0=Q,1=K,2=V (wave-uniform)
            const int hd = n - which * 768;
            const int h = hd >> 6, dd = hd & 63;
            #pragma unroll
            for (int i = 0; i < 4; ++i) {
                #pragma unroll
                for (int r = 0; r < 4; ++r) {
                    const int m = m0 + wm + i * 16 + g * 4 + r;
                    const int b = m >> 10, tt = m & 1023;
                    const int idx = ((b * 12 + h) * 1024 + tt) * 64 + dd;
                    const float v = acc[i][j][r] + bn;
                    if (which == 0) {
                        // fold 1/sqrt(64) and log2(e) so attn exp2 needs no mul
                        qbf[idx] = f2bf(v * (0.125f * 1.44269504f));
                    } else if (which == 1) {
                        outK[idx] = v; kbf[idx] = f2bf(v);
                    } else {
                        outV[idx] = v;   // V^T bf16 produced by transpose_v_kernel
                    }
                }
            }
        } else {
            #pragma unroll
            for (int i = 0; i < 4; ++i)
                #pragma unroll
                for (int r = 0; r < 4; ++r) {
                    const int m = m0 + wm + i * 16 + g * 4 + r;
                    outP[(size_t)m * 768 + n] = acc[i][j][r] + bn;
                }
        }
    }
}

// ---------------- causal flash attention, LDS-staged 2-phase pipeline ----------------
// grid (96, 8), 4 waves. Block y handles q-tiles y and 15-y (uniform 17 rounds).
// K/V tiles (64 kt x 64 d bf16, 8 KB each) double-buffered in LDS via
// global_load_lds with XOR chunk-swizzle (chunk ^= row&7) applied on the GLOBAL
// source and on the ds_read address (both-sides rule). Wave owns 16 q columns.
__global__ __launch_bounds__(256, 3) void attn_kernel(
    const u16* __restrict__ Qb, const u16* __restrict__ Kb,
    const u16* __restrict__ Vt, u16* __restrict__ Ob)
{
    __shared__ alignas(16) u16 Ks[2][4096];     // [64 kt][8 chunks of 8 u16], swizzled
    __shared__ alignas(16) u16 Vs[2][4096];     // [64 d ][8 chunks of 8 u16], swizzled
    __shared__ alignas(16) u16 Pl[4][16 * 72];  // per-wave P: 16 q x (64+8 pad) u16
    const int bh = blockIdx.x;
    const int t = threadIdx.x;
    const int wid = t >> 6, l = t & 63;
    const int c = l & 15, g = l >> 4;
    u16* P = Pl[wid];
    const u16* Kp = Kb + (size_t)bh * 65536;    // [T][64]
    const u16* Vp = Vt + (size_t)bh * 65536;    // [64][T]
    const int b = bh / 12, h = bh - (bh / 12) * 12;

    const int srow = t >> 3;
    const int sch  = (t & 7) ^ (srow & 7);
    const u16* Ksrc0 = Kp + (size_t)srow * 64 + sch * 8;
    const u16* Ksrc1 = Kp + (size_t)(srow + 32) * 64 + sch * 8;
    const u16* Vsrc0 = Vp + (size_t)srow * 1024 + sch * 8;
    const u16* Vsrc1 = Vp + (size_t)(srow + 32) * 1024 + sch * 8;

    // fragment read offsets (u16): row c (within 16-row subtile), logical chunk g / g+4
    const int fo0 = c * 64 + ((g ^ (c & 7)) * 8);
    const int fo1 = c * 64 + (((g + 4) ^ (c & 7)) * 8);

#define STAGE(buf, kt0) do {                                        \
        gload16(Ksrc0 + (size_t)(kt0) * 64, Ks[buf] + t * 8);       \
        gload16(Ksrc1 + (size_t)(kt0) * 64, Ks[buf] + 2048 + t * 8);\
        gload16(Vsrc0 + (kt0),              Vs[buf] + t * 8);       \
        gload16(Vsrc1 + (kt0),              Vs[buf] + 2048 + t * 8);\
    } while (0)

    #pragma unroll 1
    for (int pass = 0; pass < 2; ++pass) {
        const int tile = pass ? (15 - blockIdx.y) : blockIdx.y;
        const int qbase = tile * 64 + wid * 16;
        const int qg = qbase + c;                // this lane's q column
        const u16* Qp = Qb + ((size_t)bh * 1024 + qg) * 64 + g * 8;
        const short8 bq0 = *(const short8*)(Qp);
        const short8 bq1 = *(const short8*)(Qp + 32);

        f32x4 oacc[4] = {};
        float mrow = -INF, lpart = 0.f;
        const int nb = tile + 1;                 // 64-wide KV blocks

        STAGE(0, 0);
        __syncthreads();
        int cur = 0;

        #pragma unroll 1
        for (int kb = 0; kb < nb; ++kb) {
            if (kb + 1 < nb) STAGE(cur ^ 1, (kb + 1) << 6);
            const u16* kB = Ks[cur];
            const u16* vB = Vs[cur];
            short8 af0[4], af1[4], vf0[4], vf1[4];
            #pragma unroll
            for (int j = 0; j < 4; ++j) {
                af0[j] = *(const short8*)(kB + j * 1024 + fo0);
                af1[j] = *(const short8*)(kB + j * 1024 + fo1);
            }
            #pragma unroll
            for (int dt = 0; dt < 4; ++dt) {
                vf0[dt] = *(const short8*)(vB + dt * 1024 + fo0);
                vf1[dt] = *(const short8*)(vB + dt * 1024 + fo1);
            }
            // QK^T: D[kt][q], s[j] covers kt rows j*16 + g*4 + r
            f32x4 s[4] = {};
            __builtin_amdgcn_s_setprio(1);
            #pragma unroll
            for (int j = 0; j < 4; ++j) {
                s[j] = MFMA16x16x32(af0[j], bq0, s[j], 0, 0, 0);
                s[j] = MFMA16x16x32(af1[j], bq1, s[j], 0, 0, 0);
            }
            __builtin_amdgcn_s_setprio(0);
            if (kb == nb - 1) {                  // only diagonal block masks
                const int kt0 = kb << 6;
                #pragma unroll
                for (int j = 0; j < 4; ++j)
                    #pragma unroll
                    for (int r = 0; r < 4; ++r)
                        if (kt0 + j * 16 + g * 4 + r > qg) s[j][r] = -INF;
            }
            // softmax (scores already in log2 units); tree max
            f32x4 mm = max4(max4(s[0], s[1]), max4(s[2], s[3]));
            float tm = fmaxf(fmaxf(mm.x, mm.y), fmaxf(mm.z, mm.w));
            tm = fmaxf(tm, __shfl_xor(tm, 16));
            tm = fmaxf(tm, __shfl_xor(tm, 32));
            // defer-max (T13): skip rescale while growth <= 8 (log2 units; P <= 256)
            const bool keep = (__all(tm <= mrow + 8.f) != 0);
            const float mnew = keep ? mrow : fmaxf(mrow, tm);
            if (!keep) {
                const float sc = exp2f(mrow - mnew);
                mrow = mnew;
                lpart *= sc;
                #pragma unroll
                for (int dt = 0; dt < 4; ++dt) {
                    oacc[dt][0] *= sc; oacc[dt][1] *= sc;
                    oacc[dt][2] *= sc; oacc[dt][3] *= sc;
                }
            }
            f32x4 p[4];
            #pragma unroll
            for (int j = 0; j < 4; ++j) {
                p[j].x = exp2f(s[j].x - mnew); p[j].y = exp2f(s[j].y - mnew);
                p[j].z = exp2f(s[j].z - mnew); p[j].w = exp2f(s[j].w - mnew);
            }
            f32x4 ps = add4(add4(p[0], p[1]), add4(p[2], p[3]));
            lpart += (ps.x + ps.y) + (ps.z + ps.w);   // per-lane partial (g-reduce deferred)
            // P[q=c][kt] bf16 -> LDS (row stride 72 u16 = 144 B, 2-way conflicts only)
            #pragma unroll
            for (int j = 0; j < 4; ++j) {
                short4v w;
                w.x = (short)f2bf(p[j].x); w.y = (short)f2bf(p[j].y);
                w.z = (short)f2bf(p[j].z); w.w = (short)f2bf(p[j].w);
                *(short4v*)(P + c * 72 + j * 16 + g * 4) = w;
            }
            const short8 pf0 = *(const short8*)(P + c * 72 + g * 8);
            const short8 pf1 = *(const short8*)(P + c * 72 + 32 + g * 8);
            // PV: A = V^T rows (d), B = P^T -> D[d][q]
            __builtin_amdgcn_s_setprio(1);
            #pragma unroll
            for (int dt = 0; dt < 4; ++dt) {
                oacc[dt] = MFMA16x16x32(vf0[dt], pf0, oacc[dt], 0, 0, 0);
                oacc[dt] = MFMA16x16x32(vf1[dt], pf1, oacc[dt], 0, 0, 0);
            }
            __builtin_amdgcn_s_setprio(0);
            __syncthreads();   // drains staging (vmcnt 0) + all waves done with buf cur
            cur ^= 1;
        }
        float lsum = lpart;
        lsum += __shfl_xor(lsum, 16);
        lsum += __shfl_xor(lsum, 32);
        const float li = 1.f / lsum;             // lane-local (col=q layout)
        #pragma unroll
        for (int dt = 0; dt < 4; ++dt) {
            short4v o;
            o.x = (short)f2bf(oacc[dt][0] * li);
            o.y = (short)f2bf(oacc[dt][1] * li);
            o.z = (short)f2bf(oacc[dt][2] * li);
            o.w = (short)f2bf(oacc[dt][3] * li);
            *(short4v*)(Ob + (size_t)(b * 1024 + qg) * 768 + h * 64 + dt * 16 + g * 4) = o;
        }
    }
#undef STAGE
}

extern "C" void kernel_launch(void* const* d_in, const int* in_sizes, int n_in,
                              void* d_out, int out_size, void* d_ws, size_t ws_size,
                              hipStream_t stream) {
    const float* hs = (const float*)d_in[0];   // [8,1024,768]
    const float* Wa = (const float*)d_in[1];   // [768,2304]
    const float* ba = (const float*)d_in[2];   // [2304]
    const float* Wp = (const float*)d_in[3];   // [768,768]
    const float* bp = (const float*)d_in[4];   // [768]
    float* out = (float*)d_out;                // out | K | V  (each NOUT fp32)

    u16* ws  = (u16*)d_ws;
    u16* Xbf = ws;                             // [8192][768]
    u16* WaT = Xbf + NOUT;                     // [2304][768]
    u16* WpT = WaT + 768 * 2304;               // [768][768]
    u16* Qbf = WpT + 768 * 768;                // [B,H,T,64] (pre-scaled by 0.125*log2e)
    u16* Kbf = Qbf + NOUT;                     // [B,H,T,64]
    u16* VTb = Kbf + NOUT;                     // [B,H,64,T]
    u16* Obf = VTb + NOUT;                     // [8192][768]

    cvt_bf16_kernel<<<NOUT / 1024, 256, 0, stream>>>(hs, Xbf, NOUT);
    transpose_bf16_kernel<<<dim3(2304 / 32, 768 / 32), 256, 0, stream>>>(Wa, WaT, 768, 2304);
    transpose_bf16_kernel<<<dim3(768 / 32, 768 / 32), 256, 0, stream>>>(Wp, WpT, 768, 768);
    gemm_k768_kernel<0><<<dim3(64, 18), 256, 0, stream>>>(
        Xbf, WaT, ba, Qbf, Kbf, out + NOUT, out + 2 * (size_t)NOUT, nullptr);
    transpose_v_kernel<<<dim3(32, 2, 96), 256, 0, stream>>>(out + 2 * (size_t)NOUT, VTb);
    attn_kernel<<<dim3(96, 8), 256, 0, stream>>>(Qbf, Kbf, VTb, Obf);
    gemm_k768_kernel<1><<<dim3(64, 6), 256, 0, stream>>>(
        Obf, WpT, bp, nullptr, nullptr, nullptr, nullptr, out);
}

// Round 8
// 128.846 us; speedup vs baseline: 1.1248x; 1.0140x over previous
//
#include <hip/hip_runtime.h>
#include <stdint.h>

// Problem constants
#define B_SZ 8
#define T_SZ 1024
#define DM   768
#define NH   12
#define DH   64
#define NTOK (B_SZ * T_SZ)   // 8192
#define NOUT (NTOK * DM)     // 6291456
#define INF  __builtin_inff()

typedef unsigned short u16;
typedef __attribute__((ext_vector_type(8))) short short8;   // 8 bf16 (4 VGPRs) MFMA frag
typedef __attribute__((ext_vector_type(4))) short short4v;
typedef __attribute__((ext_vector_type(4))) float f32x4;

#define MFMA16x16x32 __builtin_amdgcn_mfma_f32_16x16x32_bf16

__device__ __forceinline__ u16 f2bf(float f) {
    unsigned u = __builtin_bit_cast(unsigned, f);
    u += 0x7fffu + ((u >> 16) & 1u);   // RNE
    return (u16)(u >> 16);
}

__device__ __forceinline__ f32x4 max4(f32x4 a, f32x4 b) {
    f32x4 r; r.x = fmaxf(a.x, b.x); r.y = fmaxf(a.y, b.y);
    r.z = fmaxf(a.z, b.z); r.w = fmaxf(a.w, b.w); return r;
}
__device__ __forceinline__ f32x4 add4(f32x4 a, f32x4 b) {
    f32x4 r; r.x = a.x + b.x; r.y = a.y + b.y;
    r.z = a.z + b.z; r.w = a.w + b.w; return r;
}

// CK-proven pattern: integer-cast to AS1/AS3 pointers for the direct-to-LDS load.
__device__ __forceinline__ void gload16(const void* g, void* l) {
    __builtin_amdgcn_global_load_lds(
        (const __attribute__((address_space(1))) unsigned int*)(unsigned long long)(uintptr_t)g,
        (__attribute__((address_space(3))) unsigned int*)(unsigned int)(uintptr_t)l,
        16, 0, 0);
}

// ---------------- fp32 -> bf16 elementwise ----------------
__global__ __launch_bounds__(256) void cvt_bf16_kernel(const float* __restrict__ in,
                                                       u16* __restrict__ out, int n) {
    int i = (blockIdx.x * 256 + threadIdx.x) * 4;
    if (i >= n) return;
    f32x4 v = *(const f32x4*)(in + i);
    short4v o;
    o.x = (short)f2bf(v.x); o.y = (short)f2bf(v.y);
    o.z = (short)f2bf(v.z); o.w = (short)f2bf(v.w);
    *(short4v*)(out + i) = o;
}

// ---------------- transpose fp32 [R][C] -> bf16 [C][R] ----------------
__global__ __launch_bounds__(256) void transpose_bf16_kernel(const float* __restrict__ in,
                                                             u16* __restrict__ out,
                                                             int R, int C) {
    __shared__ float tile[32][33];
    int tx = threadIdx.x & 31, ty = threadIdx.x >> 5;   // 32 x 8
    int c0 = blockIdx.x * 32, r0 = blockIdx.y * 32;
    for (int i = ty; i < 32; i += 8)
        tile[i][tx] = in[(size_t)(r0 + i) * C + c0 + tx];
    __syncthreads();
    for (int i = ty; i < 32; i += 8)
        out[(size_t)(c0 + i) * R + r0 + tx] = f2bf(tile[tx][i]);
}

// ---------------- per-head V transpose: fp32 [96][1024][64] -> bf16 [96][64][1024] ----------------
__global__ __launch_bounds__(256) void transpose_v_kernel(const float* __restrict__ in,
                                                          u16* __restrict__ out) {
    __shared__ float tile[32][33];
    const int head = blockIdx.z;
    const int t0 = blockIdx.x * 32, d0 = blockIdx.y * 32;
    const float* ip = in + (size_t)head * 65536;
    u16* op = out + (size_t)head * 65536;
    int tx = threadIdx.x & 31, ty = threadIdx.x >> 5;
    for (int i = ty; i < 32; i += 8)
        tile[i][tx] = ip[(size_t)(t0 + i) * 64 + d0 + tx];
    __syncthreads();
    for (int i = ty; i < 32; i += 8)
        op[(size_t)(d0 + i) * 1024 + t0 + tx] = f2bf(tile[tx][i]);
}

// ---------------- bf16 GEMM, K=768, 128x128 tile, 3-deep pipeline + counted vmcnt ----------------
// A [M][768] bf16 row-major, BT [N][768] bf16 (B transposed).
// 3 LDS buffers (48 KB total) -> 3 blocks/CU co-resident (round-7 lesson: the
// 4-buf/64 KB variant dropped occupancy to 2 blocks and lost its pipeline gain).
// Tile kt+3 staged into the buffer freed by kt; per-iter wait vmcnt(8) — tile
// kt+1 landed, kt+2/kt+3 stay in flight (T4 never-drain). Raw s_barrier.
// Swizzle phys_chunk = chunk ^ ((row>>1)&3): verified 0 bank conflicts (r7).
template <int EPI>
__global__ __launch_bounds__(256, 3) void gemm_k768_kernel(
    const u16* __restrict__ A, const u16* __restrict__ BT, const float* __restrict__ bias,
    u16* __restrict__ qbf, u16* __restrict__ kbf,
    float* __restrict__ outK, float* __restrict__ outV, float* __restrict__ outP)
{
    __shared__ alignas(16) u16 As[3][128 * 32];   // 8 KB each
    __shared__ alignas(16) u16 Bs[3][128 * 32];
    const int t   = threadIdx.x;
    const int wid = t >> 6, l = t & 63;
    const int lr  = l & 15, g = l >> 4;
    const int m0  = blockIdx.x * 128, n0 = blockIdx.y * 128;
    const int wm  = (wid >> 1) * 64, wn = (wid & 1) * 64;

    // staging: thread t carries rows srow and srow+64, phys slot t&3,
    // logical chunk = (t&3) ^ ((srow>>1)&3)   (same for srow+64)
    const int srow = t >> 2;
    const int sch  = ((t & 3) ^ ((srow >> 1) & 3)) * 8;
    const u16* ga0 = A  + (size_t)(m0 + srow) * 768 + sch;
    const u16* ga1 = A  + (size_t)(m0 + 64 + srow) * 768 + sch;
    const u16* gb0 = BT + (size_t)(n0 + srow) * 768 + sch;
    const u16* gb1 = BT + (size_t)(n0 + 64 + srow) * 768 + sch;

#define GSTAGE(buf, kt) do {                              \
        gload16(ga0 + (kt) * 32, As[buf] + t * 8);        \
        gload16(ga1 + (kt) * 32, As[buf] + 2048 + t * 8); \
        gload16(gb0 + (kt) * 32, Bs[buf] + t * 8);        \
        gload16(gb1 + (kt) * 32, Bs[buf] + 2048 + t * 8); \
    } while (0)

    // fragment read chunk offset (u16): logical chunk g at row (..+lr)
    const int fco = (g ^ ((lr >> 1) & 3)) * 8;

    f32x4 acc[4][4] = {};
    GSTAGE(0, 0); GSTAGE(1, 1); GSTAGE(2, 2);             // 12 loads in flight
    asm volatile("s_waitcnt vmcnt(8)" ::: "memory");      // tile 0 landed
    __builtin_amdgcn_s_barrier();
    __builtin_amdgcn_sched_barrier(0);

    int buf = 0;
    #pragma unroll 1
    for (int kt = 0; kt < 24; ++kt) {
        const u16* aB = As[buf];
        const u16* bB = Bs[buf];
        short8 af[4], bfr[4];
        #pragma unroll
        for (int i = 0; i < 4; ++i)
            af[i] = *(const short8*)(aB + (wm + i * 16 + lr) * 32 + fco);
        #pragma unroll
        for (int j = 0; j < 4; ++j)
            bfr[j] = *(const short8*)(bB + (wn + j * 16 + lr) * 32 + fco);
        __builtin_amdgcn_s_setprio(1);
        #pragma unroll
        for (int i = 0; i < 4; ++i)
            #pragma unroll
            for (int j = 0; j < 4; ++j)
                acc[i][j] = MFMA16x16x32(af[i], bfr[j], acc[i][j], 0, 0, 0);
        __builtin_amdgcn_s_setprio(0);
        // barrier 1: all waves done READING buf (ds_reads consumed by MFMA above)
        __builtin_amdgcn_s_barrier();
        __builtin_amdgcn_sched_barrier(0);
        if (kt + 3 < 24) GSTAGE(buf, kt + 3);             // reuse freed buffer
        // counted wait: tile kt+1 landed; kt+2 (and kt+3) stay in flight
        if (kt < 21)       asm volatile("s_waitcnt vmcnt(8)" ::: "memory");
        else if (kt == 21) asm volatile("s_waitcnt vmcnt(4)" ::: "memory");
        else if (kt == 22) asm volatile("s_waitcnt vmcnt(0)" ::: "memory");
        // barrier 2: publish buf for tile kt+1
        __builtin_amdgcn_s_barrier();
        __builtin_amdgcn_sched_barrier(0);
        buf = (buf == 2) ? 0 : buf + 1;
    }
#undef GSTAGE

    // C/D layout: col = lane&15, row = (lane>>4)*4 + reg  [verified m89/m91]
    #pragma unroll
    for (int j = 0; j < 4; ++j) {
        const int n = n0 + wn + j * 16 + lr;
        const float bn = bias[n];
        if (EPI == 0) {
            const int which = n / 768;           // 0=Q,1=K,2=V (wave-uniform)
            const int hd = n - which * 768;
            const int h = hd >> 6, dd = hd & 63;
            #pragma unroll
            for (int i = 0; i < 4; ++i) {
                #pragma unroll
                for (int r = 0; r < 4; ++r) {
                    const int m = m0 + wm + i * 16 + g * 4 + r;
                    const int b = m >> 10, tt = m & 1023;
                    const int idx = ((b * 12 + h) * 1024 + tt) * 64 + dd;
                    const float v = acc[i][j][r] + bn;
                    if (which == 0) {
                        // fold 1/sqrt(64) and log2(e) so attn exp2 needs no mul
                        qbf[idx] = f2bf(v * (0.125f * 1.44269504f));
                    } else if (which == 1) {
                        outK[idx] = v; kbf[idx] = f2bf(v);
                    } else {
                        outV[idx] = v;   // V^T bf16 produced by transpose_v_kernel
                    }
                }
            }
        } else {
            #pragma unroll
            for (int i = 0; i < 4; ++i)
                #pragma unroll
                for (int r = 0; r < 4; ++r) {
                    const int m = m0 + wm + i * 16 + g * 4 + r;
                    outP[(size_t)m * 768 + n] = acc[i][j][r] + bn;
                }
        }
    }
}

// ---------------- causal flash attention, LDS-staged 2-phase pipeline ----------------
// grid (96, 8), 4 waves. Block y handles q-tiles y and 15-y (uniform 17 rounds).
// K/V tiles (64 kt x 64 d bf16, 8 KB each) double-buffered in LDS via
// global_load_lds with XOR chunk-swizzle (chunk ^= row&7) applied on the GLOBAL
// source and on the ds_read address (both-sides rule). Wave owns 16 q columns.
__global__ __launch_bounds__(256, 3) void attn_kernel(
    const u16* __restrict__ Qb, const u16* __restrict__ Kb,
    const u16* __restrict__ Vt, u16* __restrict__ Ob)
{
    __shared__ alignas(16) u16 Ks[2][4096];     // [64 kt][8 chunks of 8 u16], swizzled
    __shared__ alignas(16) u16 Vs[2][4096];     // [64 d ][8 chunks of 8 u16], swizzled
    __shared__ alignas(16) u16 Pl[4][16 * 72];  // per-wave P: 16 q x (64+8 pad) u16
    const int bh = blockIdx.x;
    const int t = threadIdx.x;
    const int wid = t >> 6, l = t & 63;
    const int c = l & 15, g = l >> 4;
    u16* P = Pl[wid];
    const u16* Kp = Kb + (size_t)bh * 65536;    // [T][64]
    const u16* Vp = Vt + (size_t)bh * 65536;    // [64][T]
    const int b = bh / 12, h = bh - (bh / 12) * 12;

    const int srow = t >> 3;
    const int sch  = (t & 7) ^ (srow & 7);
    const u16* Ksrc0 = Kp + (size_t)srow * 64 + sch * 8;
    const u16* Ksrc1 = Kp + (size_t)(srow + 32) * 64 + sch * 8;
    const u16* Vsrc0 = Vp + (size_t)srow * 1024 + sch * 8;
    const u16* Vsrc1 = Vp + (size_t)(srow + 32) * 1024 + sch * 8;

    // fragment read offsets (u16): row c (within 16-row subtile), logical chunk g / g+4
    const int fo0 = c * 64 + ((g ^ (c & 7)) * 8);
    const int fo1 = c * 64 + (((g + 4) ^ (c & 7)) * 8);

#define STAGE(buf, kt0) do {                                        \
        gload16(Ksrc0 + (size_t)(kt0) * 64, Ks[buf] + t * 8);       \
        gload16(Ksrc1 + (size_t)(kt0) * 64, Ks[buf] + 2048 + t * 8);\
        gload16(Vsrc0 + (kt0),              Vs[buf] + t * 8);       \
        gload16(Vsrc1 + (kt0),              Vs[buf] + 2048 + t * 8);\
    } while (0)

    #pragma unroll 1
    for (int pass = 0; pass < 2; ++pass) {
        const int tile = pass ? (15 - blockIdx.y) : blockIdx.y;
        const int qbase = tile * 64 + wid * 16;
        const int qg = qbase + c;                // this lane's q column
        const u16* Qp = Qb + ((size_t)bh * 1024 + qg) * 64 + g * 8;
        const short8 bq0 = *(const short8*)(Qp);
        const short8 bq1 = *(const short8*)(Qp + 32);

        f32x4 oacc[4] = {};
        float mrow = -INF, lpart = 0.f;
        const int nb = tile + 1;                 // 64-wide KV blocks

        STAGE(0, 0);
        __syncthreads();
        int cur = 0;

        #pragma unroll 1
        for (int kb = 0; kb < nb; ++kb) {
            if (kb + 1 < nb) STAGE(cur ^ 1, (kb + 1) << 6);
            const u16* kB = Ks[cur];
            const u16* vB = Vs[cur];
            short8 af0[4], af1[4], vf0[4], vf1[4];
            #pragma unroll
            for (int j = 0; j < 4; ++j) {
                af0[j] = *(const short8*)(kB + j * 1024 + fo0);
                af1[j] = *(const short8*)(kB + j * 1024 + fo1);
            }
            #pragma unroll
            for (int dt = 0; dt < 4; ++dt) {
                vf0[dt] = *(const short8*)(vB + dt * 1024 + fo0);
                vf1[dt] = *(const short8*)(vB + dt * 1024 + fo1);
            }
            // QK^T: D[kt][q], s[j] covers kt rows j*16 + g*4 + r
            f32x4 s[4] = {};
            __builtin_amdgcn_s_setprio(1);
            #pragma unroll
            for (int j = 0; j < 4; ++j) {
                s[j] = MFMA16x16x32(af0[j], bq0, s[j], 0, 0, 0);
                s[j] = MFMA16x16x32(af1[j], bq1, s[j], 0, 0, 0);
            }
            __builtin_amdgcn_s_setprio(0);
            if (kb == nb - 1) {                  // only diagonal block masks
                const int kt0 = kb << 6;
                #pragma unroll
                for (int j = 0; j < 4; ++j)
                    #pragma unroll
                    for (int r = 0; r < 4; ++r)
                        if (kt0 + j * 16 + g * 4 + r > qg) s[j][r] = -INF;
            }
            // softmax (scores already in log2 units); tree max
            f32x4 mm = max4(max4(s[0], s[1]), max4(s[2], s[3]));
            float tm = fmaxf(fmaxf(mm.x, mm.y), fmaxf(mm.z, mm.w));
            tm = fmaxf(tm, __shfl_xor(tm, 16));
            tm = fmaxf(tm, __shfl_xor(tm, 32));
            // defer-max (T13): skip rescale while growth <= 8 (log2 units; P <= 256)
            const bool keep = (__all(tm <= mrow + 8.f) != 0);
            const float mnew = keep ? mrow : fmaxf(mrow, tm);
            if (!keep) {
                const float sc = exp2f(mrow - mnew);
                mrow = mnew;
                lpart *= sc;
                #pragma unroll
                for (int dt = 0; dt < 4; ++dt) {
                    oacc[dt][0] *= sc; oacc[dt][1] *= sc;
                    oacc[dt][2] *= sc; oacc[dt][3] *= sc;
                }
            }
            f32x4 p[4];
            #pragma unroll
            for (int j = 0; j < 4; ++j) {
                p[j].x = exp2f(s[j].x - mnew); p[j].y = exp2f(s[j].y - mnew);
                p[j].z = exp2f(s[j].z - mnew); p[j].w = exp2f(s[j].w - mnew);
            }
            f32x4 ps = add4(add4(p[0], p[1]), add4(p[2], p[3]));
            lpart += (ps.x + ps.y) + (ps.z + ps.w);   // per-lane partial (g-reduce deferred)
            // P[q=c][kt] bf16 -> LDS (row stride 72 u16 = 144 B, 2-way conflicts only)
            #pragma unroll
            for (int j = 0; j < 4; ++j) {
                short4v w;
                w.x = (short)f2bf(p[j].x); w.y = (short)f2bf(p[j].y);
                w.z = (short)f2bf(p[j].z); w.w = (short)f2bf(p[j].w);
                *(short4v*)(P + c * 72 + j * 16 + g * 4) = w;
            }
            const short8 pf0 = *(const short8*)(P + c * 72 + g * 8);
            const short8 pf1 = *(const short8*)(P + c * 72 + 32 + g * 8);
            // PV: A = V^T rows (d), B = P^T -> D[d][q]
            __builtin_amdgcn_s_setprio(1);
            #pragma unroll
            for (int dt = 0; dt < 4; ++dt) {
                oacc[dt] = MFMA16x16x32(vf0[dt], pf0, oacc[dt], 0, 0, 0);
                oacc[dt] = MFMA16x16x32(vf1[dt], pf1, oacc[dt], 0, 0, 0);
            }
            __builtin_amdgcn_s_setprio(0);
            __syncthreads();   // drains staging (vmcnt 0) + all waves done with buf cur
            cur ^= 1;
        }
        float lsum = lpart;
        lsum += __shfl_xor(lsum, 16);
        lsum += __shfl_xor(lsum, 32);
        const float li = 1.f / lsum;             // lane-local (col=q layout)
        #pragma unroll
        for (int dt = 0; dt < 4; ++dt) {
            short4v o;
            o.x = (short)f2bf(oacc[dt][0] * li);
            o.y = (short)f2bf(oacc[dt][1] * li);
            o.z = (short)f2bf(oacc[dt][2] * li);
            o.w = (short)f2bf(oacc[dt][3] * li);
            *(short4v*)(Ob + (size_t)(b * 1024 + qg) * 768 + h * 64 + dt * 16 + g * 4) = o;
        }
    }
#undef STAGE
}

extern "C" void kernel_launch(void* const* d_in, const int* in_sizes, int n_in,
                              void* d_out, int out_size, void* d_ws, size_t ws_size,
                              hipStream_t stream) {
    const float* hs = (const float*)d_in[0];   // [8,1024,768]
    const float* Wa = (const float*)d_in[1];   // [768,2304]
    const float* ba = (const float*)d_in[2];   // [2304]
    const float* Wp = (const float*)d_in[3];   // [768,768]
    const float* bp = (const float*)d_in[4];   // [768]
    float* out = (float*)d_out;                // out | K | V  (each NOUT fp32)

    u16* ws  = (u16*)d_ws;
    u16* Xbf = ws;                             // [8192][768]
    u16* WaT = Xbf + NOUT;                     // [2304][768]
    u16* WpT = WaT + 768 * 2304;               // [768][768]
    u16* Qbf = WpT + 768 * 768;                // [B,H,T,64] (pre-scaled by 0.125*log2e)
    u16* Kbf = Qbf + NOUT;                     // [B,H,T,64]
    u16* VTb = Kbf + NOUT;                     // [B,H,64,T]
    u16* Obf = VTb + NOUT;                     // [8192][768]

    cvt_bf16_kernel<<<NOUT / 1024, 256, 0, stream>>>(hs, Xbf, NOUT);
    transpose_bf16_kernel<<<dim3(2304 / 32, 768 / 32), 256, 0, stream>>>(Wa, WaT, 768, 2304);
    transpose_bf16_kernel<<<dim3(768 / 32, 768 / 32), 256, 0, stream>>>(Wp, WpT, 768, 768);
    gemm_k768_kernel<0><<<dim3(64, 18), 256, 0, stream>>>(
        Xbf, WaT, ba, Qbf, Kbf, out + NOUT, out + 2 * (size_t)NOUT, nullptr);
    transpose_v_kernel<<<dim3(32, 2, 96), 256, 0, stream>>>(out + 2 * (size_t)NOUT, VTb);
    attn_kernel<<<dim3(96, 8), 256, 0, stream>>>(Qbf, Kbf, VTb, Obf);
    gemm_k768_kernel<1><<<dim3(64, 6), 256, 0, stream>>>(
        Obf, WpT, bp, nullptr, nullptr, nullptr, nullptr, out);
}

// Round 9
// 126.727 us; speedup vs baseline: 1.1436x; 1.0167x over previous
//
#include <hip/hip_runtime.h>
#include <stdint.h>

// Problem constants
#define B_SZ 8
#define T_SZ 1024
#define DM   768
#define NH   12
#define DH   64
#define NTOK (B_SZ * T_SZ)   // 8192
#define NOUT (NTOK * DM)     // 6291456
#define INF  __builtin_inff()

typedef unsigned short u16;
typedef __attribute__((ext_vector_type(8))) short short8;   // 8 bf16 (4 VGPRs) MFMA frag
typedef __attribute__((ext_vector_type(4))) short short4v;
typedef __attribute__((ext_vector_type(4))) float f32x4;

#define MFMA16x16x32 __builtin_amdgcn_mfma_f32_16x16x32_bf16

__device__ __forceinline__ u16 f2bf(float f) {
    unsigned u = __builtin_bit_cast(unsigned, f);
    u += 0x7fffu + ((u >> 16) & 1u);   // RNE
    return (u16)(u >> 16);
}

__device__ __forceinline__ f32x4 max4(f32x4 a, f32x4 b) {
    f32x4 r; r.x = fmaxf(a.x, b.x); r.y = fmaxf(a.y, b.y);
    r.z = fmaxf(a.z, b.z); r.w = fmaxf(a.w, b.w); return r;
}
__device__ __forceinline__ f32x4 add4(f32x4 a, f32x4 b) {
    f32x4 r; r.x = a.x + b.x; r.y = a.y + b.y;
    r.z = a.z + b.z; r.w = a.w + b.w; return r;
}

// CK-proven pattern: integer-cast to AS1/AS3 pointers for the direct-to-LDS load.
__device__ __forceinline__ void gload16(const void* g, void* l) {
    __builtin_amdgcn_global_load_lds(
        (const __attribute__((address_space(1))) unsigned int*)(unsigned long long)(uintptr_t)g,
        (__attribute__((address_space(3))) unsigned int*)(unsigned int)(uintptr_t)l,
        16, 0, 0);
}

// ---------------- fp32 -> bf16 elementwise ----------------
__global__ __launch_bounds__(256) void cvt_bf16_kernel(const float* __restrict__ in,
                                                       u16* __restrict__ out, int n) {
    int i = (blockIdx.x * 256 + threadIdx.x) * 4;
    if (i >= n) return;
    f32x4 v = *(const f32x4*)(in + i);
    short4v o;
    o.x = (short)f2bf(v.x); o.y = (short)f2bf(v.y);
    o.z = (short)f2bf(v.z); o.w = (short)f2bf(v.w);
    *(short4v*)(out + i) = o;
}

// ---------------- transpose fp32 [R][C] -> bf16 [C][R] ----------------
__global__ __launch_bounds__(256) void transpose_bf16_kernel(const float* __restrict__ in,
                                                             u16* __restrict__ out,
                                                             int R, int C) {
    __shared__ float tile[32][33];
    int tx = threadIdx.x & 31, ty = threadIdx.x >> 5;   // 32 x 8
    int c0 = blockIdx.x * 32, r0 = blockIdx.y * 32;
    for (int i = ty; i < 32; i += 8)
        tile[i][tx] = in[(size_t)(r0 + i) * C + c0 + tx];
    __syncthreads();
    for (int i = ty; i < 32; i += 8)
        out[(size_t)(c0 + i) * R + r0 + tx] = f2bf(tile[tx][i]);
}

// ---------------- per-head V transpose: fp32 [96][1024][64] -> bf16 [96][64][1024] ----------------
__global__ __launch_bounds__(256) void transpose_v_kernel(const float* __restrict__ in,
                                                          u16* __restrict__ out) {
    __shared__ float tile[32][33];
    const int head = blockIdx.z;
    const int t0 = blockIdx.x * 32, d0 = blockIdx.y * 32;
    const float* ip = in + (size_t)head * 65536;
    u16* op = out + (size_t)head * 65536;
    int tx = threadIdx.x & 31, ty = threadIdx.x >> 5;
    for (int i = ty; i < 32; i += 8)
        tile[i][tx] = ip[(size_t)(t0 + i) * 64 + d0 + tx];
    __syncthreads();
    for (int i = ty; i < 32; i += 8)
        op[(size_t)(d0 + i) * 1024 + t0 + tx] = f2bf(tile[tx][i]);
}

// ---------------- bf16 GEMM, K=768, 128x128 tile, 3-buf / 1-barrier pipeline ----------------
// A [M][768] bf16 row-major, BT [N][768] bf16 (B transposed).
// 3 LDS buffers (48 KB -> 3 blocks/CU). Stage distance 2, ONE barrier per
// K-step: {stage kt+2 ; ds_read buf[kt%3] ; MFMA ; vmcnt(4) ; s_barrier}.
// Safety: buf[(kt+2)%3] == buf[(kt-1)%3], fully consumed before the barrier
// that ended iteration kt-1 (a wave's ds_reads complete before its MFMAs,
// which precede the barrier). Counted vmcnt(4) = tile kt+1 landed, tile kt+2
// in flight (T4 never-drain; 0 only in the tail). Hand 7x3 structure keeps
// all LDS buffer indices compile-time. Swizzle chunk^((row>>1)&3): 0 conflicts (r7).
template <int EPI>
__global__ __launch_bounds__(256, 3) void gemm_k768_kernel(
    const u16* __restrict__ A, const u16* __restrict__ BT, const float* __restrict__ bias,
    u16* __restrict__ qbf, u16* __restrict__ kbf,
    float* __restrict__ outK, float* __restrict__ outV, float* __restrict__ outP)
{
    __shared__ alignas(16) u16 As[3][128 * 32];   // 8 KB each
    __shared__ alignas(16) u16 Bs[3][128 * 32];
    const int t   = threadIdx.x;
    const int wid = t >> 6, l = t & 63;
    const int lr  = l & 15, g = l >> 4;
    const int m0  = blockIdx.x * 128, n0 = blockIdx.y * 128;
    const int wm  = (wid >> 1) * 64, wn = (wid & 1) * 64;

    // staging: thread t carries rows srow and srow+64, phys slot t&3,
    // logical chunk = (t&3) ^ ((srow>>1)&3)   (same for srow+64)
    const int srow = t >> 2;
    const int sch  = ((t & 3) ^ ((srow >> 1) & 3)) * 8;
    const u16* ga0 = A  + (size_t)(m0 + srow) * 768 + sch;
    const u16* ga1 = A  + (size_t)(m0 + 64 + srow) * 768 + sch;
    const u16* gb0 = BT + (size_t)(n0 + srow) * 768 + sch;
    const u16* gb1 = BT + (size_t)(n0 + 64 + srow) * 768 + sch;

#define GSTAGE(buf, kt) do {                              \
        gload16(ga0 + (kt) * 32, As[buf] + t * 8);        \
        gload16(ga1 + (kt) * 32, As[buf] + 2048 + t * 8); \
        gload16(gb0 + (kt) * 32, Bs[buf] + t * 8);        \
        gload16(gb1 + (kt) * 32, Bs[buf] + 2048 + t * 8); \
    } while (0)

    // fragment read chunk offset (u16): logical chunk g at row (..+lr)
    const int fco = (g ^ ((lr >> 1) & 3)) * 8;

    f32x4 acc[4][4] = {};

#define COMPUTE(buf) do {                                                 \
        const u16* aB = As[buf];                                          \
        const u16* bB = Bs[buf];                                          \
        short8 af[4], bfr[4];                                             \
        _Pragma("unroll")                                                 \
        for (int i = 0; i < 4; ++i)                                       \
            af[i] = *(const short8*)(aB + (wm + i * 16 + lr) * 32 + fco); \
        _Pragma("unroll")                                                 \
        for (int j = 0; j < 4; ++j)                                       \
            bfr[j] = *(const short8*)(bB + (wn + j * 16 + lr) * 32 + fco);\
        __builtin_amdgcn_s_setprio(1);                                    \
        _Pragma("unroll")                                                 \
        for (int i = 0; i < 4; ++i)                                       \
            _Pragma("unroll")                                             \
            for (int j = 0; j < 4; ++j)                                   \
                acc[i][j] = MFMA16x16x32(af[i], bfr[j], acc[i][j], 0, 0, 0);\
        __builtin_amdgcn_s_setprio(0);                                    \
    } while (0)

#define WAITBAR(N) do {                                           \
        asm volatile("s_waitcnt vmcnt(" #N ")" ::: "memory");     \
        __builtin_amdgcn_s_barrier();                             \
        __builtin_amdgcn_sched_barrier(0);                        \
    } while (0)

    // prologue: tiles 0,1 staged (8 loads); wait tile 0
    GSTAGE(0, 0); GSTAGE(1, 1);
    WAITBAR(4);

    // main: kt = 0..20 as 7 x (3-step), buffer indices static
    #pragma unroll 1
    for (int i = 0; i < 7; ++i) {
        const int kt = i * 3;
        GSTAGE(2, kt + 2); COMPUTE(0); WAITBAR(4);
        GSTAGE(0, kt + 3); COMPUTE(1); WAITBAR(4);
        GSTAGE(1, kt + 4); COMPUTE(2); WAITBAR(4);
    }
    // tail: kt = 21, 22, 23
    GSTAGE(2, 23); COMPUTE(0); WAITBAR(4);   // tile 22 landed, 23 in flight
    COMPUTE(1); WAITBAR(0);                  // tile 23 landed
    COMPUTE(2);                              // last tile; no barrier needed
#undef GSTAGE
#undef COMPUTE
#undef WAITBAR

    // C/D layout: col = lane&15, row = (lane>>4)*4 + reg  [verified m89/m91]
    #pragma unroll
    for (int j = 0; j < 4; ++j) {
        const int n = n0 + wn + j * 16 + lr;
        const float bn = bias[n];
        if (EPI == 0) {
            const int which = n / 768;           // 0=Q,1=K,2=V (wave-uniform)
            const int hd = n - which * 768;
            const int h = hd >> 6, dd = hd & 63;
            #pragma unroll
            for (int i = 0; i < 4; ++i) {
                #pragma unroll
                for (int r = 0; r < 4; ++r) {
                    const int m = m0 + wm + i * 16 + g * 4 + r;
                    const int b = m >> 10, tt = m & 1023;
                    const int idx = ((b * 12 + h) * 1024 + tt) * 64 + dd;
                    const float v = acc[i][j][r] + bn;
                    if (which == 0) {
                        // fold 1/sqrt(64) and log2(e) so attn exp2 needs no mul
                        qbf[idx] = f2bf(v * (0.125f * 1.44269504f));
                    } else if (which == 1) {
                        outK[idx] = v; kbf[idx] = f2bf(v);
                    } else {
                        outV[idx] = v;   // V^T bf16 produced by transpose_v_kernel
                    }
                }
            }
        } else {
            #pragma unroll
            for (int i = 0; i < 4; ++i)
                #pragma unroll
                for (int r = 0; r < 4; ++r) {
                    const int m = m0 + wm + i * 16 + g * 4 + r;
                    outP[(size_t)m * 768 + n] = acc[i][j][r] + bn;
                }
        }
    }
}

// ---------------- causal flash attention, LDS-staged 2-phase pipeline ----------------
// grid (96, 8), 4 waves. Block y handles q-tiles y and 15-y (uniform 17 rounds).
// K/V tiles (64 kt x 64 d bf16, 8 KB each) double-buffered in LDS via
// global_load_lds with XOR chunk-swizzle (chunk ^= row&7) applied on the GLOBAL
// source and on the ds_read address (both-sides rule). Wave owns 16 q columns.
__global__ __launch_bounds__(256, 3) void attn_kernel(
    const u16* __restrict__ Qb, const u16* __restrict__ Kb,
    const u16* __restrict__ Vt, u16* __restrict__ Ob)
{
    __shared__ alignas(16) u16 Ks[2][4096];     // [64 kt][8 chunks of 8 u16], swizzled
    __shared__ alignas(16) u16 Vs[2][4096];     // [64 d ][8 chunks of 8 u16], swizzled
    __shared__ alignas(16) u16 Pl[4][16 * 72];  // per-wave P: 16 q x (64+8 pad) u16
    const int bh = blockIdx.x;
    const int t = threadIdx.x;
    const int wid = t >> 6, l = t & 63;
    const int c = l & 15, g = l >> 4;
    u16* P = Pl[wid];
    const u16* Kp = Kb + (size_t)bh * 65536;    // [T][64]
    const u16* Vp = Vt + (size_t)bh * 65536;    // [64][T]
    const int b = bh / 12, h = bh - (bh / 12) * 12;

    const int srow = t >> 3;
    const int sch  = (t & 7) ^ (srow & 7);
    const u16* Ksrc0 = Kp + (size_t)srow * 64 + sch * 8;
    const u16* Ksrc1 = Kp + (size_t)(srow + 32) * 64 + sch * 8;
    const u16* Vsrc0 = Vp + (size_t)srow * 1024 + sch * 8;
    const u16* Vsrc1 = Vp + (size_t)(srow + 32) * 1024 + sch * 8;

    // fragment read offsets (u16): row c (within 16-row subtile), logical chunk g / g+4
    const int fo0 = c * 64 + ((g ^ (c & 7)) * 8);
    const int fo1 = c * 64 + (((g + 4) ^ (c & 7)) * 8);

#define STAGE(buf, kt0) do {                                        \
        gload16(Ksrc0 + (size_t)(kt0) * 64, Ks[buf] + t * 8);       \
        gload16(Ksrc1 + (size_t)(kt0) * 64, Ks[buf] + 2048 + t * 8);\
        gload16(Vsrc0 + (kt0),              Vs[buf] + t * 8);       \
        gload16(Vsrc1 + (kt0),              Vs[buf] + 2048 + t * 8);\
    } while (0)

    #pragma unroll 1
    for (int pass = 0; pass < 2; ++pass) {
        const int tile = pass ? (15 - blockIdx.y) : blockIdx.y;
        const int qbase = tile * 64 + wid * 16;
        const int qg = qbase + c;                // this lane's q column
        const u16* Qp = Qb + ((size_t)bh * 1024 + qg) * 64 + g * 8;
        const short8 bq0 = *(const short8*)(Qp);
        const short8 bq1 = *(const short8*)(Qp + 32);

        f32x4 oacc[4] = {};
        float mrow = -INF, lpart = 0.f;
        const int nb = tile + 1;                 // 64-wide KV blocks

        STAGE(0, 0);
        __syncthreads();
        int cur = 0;

        #pragma unroll 1
        for (int kb = 0; kb < nb; ++kb) {
            if (kb + 1 < nb) STAGE(cur ^ 1, (kb + 1) << 6);
            const u16* kB = Ks[cur];
            const u16* vB = Vs[cur];
            short8 af0[4], af1[4], vf0[4], vf1[4];
            #pragma unroll
            for (int j = 0; j < 4; ++j) {
                af0[j] = *(const short8*)(kB + j * 1024 + fo0);
                af1[j] = *(const short8*)(kB + j * 1024 + fo1);
            }
            #pragma unroll
            for (int dt = 0; dt < 4; ++dt) {
                vf0[dt] = *(const short8*)(vB + dt * 1024 + fo0);
                vf1[dt] = *(const short8*)(vB + dt * 1024 + fo1);
            }
            // QK^T: D[kt][q], s[j] covers kt rows j*16 + g*4 + r
            f32x4 s[4] = {};
            __builtin_amdgcn_s_setprio(1);
            #pragma unroll
            for (int j = 0; j < 4; ++j) {
                s[j] = MFMA16x16x32(af0[j], bq0, s[j], 0, 0, 0);
                s[j] = MFMA16x16x32(af1[j], bq1, s[j], 0, 0, 0);
            }
            __builtin_amdgcn_s_setprio(0);
            if (kb == nb - 1) {                  // only diagonal block masks
                const int kt0 = kb << 6;
                #pragma unroll
                for (int j = 0; j < 4; ++j)
                    #pragma unroll
                    for (int r = 0; r < 4; ++r)
                        if (kt0 + j * 16 + g * 4 + r > qg) s[j][r] = -INF;
            }
            // softmax (scores already in log2 units); tree max
            f32x4 mm = max4(max4(s[0], s[1]), max4(s[2], s[3]));
            float tm = fmaxf(fmaxf(mm.x, mm.y), fmaxf(mm.z, mm.w));
            tm = fmaxf(tm, __shfl_xor(tm, 16));
            tm = fmaxf(tm, __shfl_xor(tm, 32));
            // defer-max (T13): skip rescale while growth <= 8 (log2 units; P <= 256)
            const bool keep = (__all(tm <= mrow + 8.f) != 0);
            const float mnew = keep ? mrow : fmaxf(mrow, tm);
            if (!keep) {
                const float sc = exp2f(mrow - mnew);
                mrow = mnew;
                lpart *= sc;
                #pragma unroll
                for (int dt = 0; dt < 4; ++dt) {
                    oacc[dt][0] *= sc; oacc[dt][1] *= sc;
                    oacc[dt][2] *= sc; oacc[dt][3] *= sc;
                }
            }
            f32x4 p[4];
            #pragma unroll
            for (int j = 0; j < 4; ++j) {
                p[j].x = exp2f(s[j].x - mnew); p[j].y = exp2f(s[j].y - mnew);
                p[j].z = exp2f(s[j].z - mnew); p[j].w = exp2f(s[j].w - mnew);
            }
            f32x4 ps = add4(add4(p[0], p[1]), add4(p[2], p[3]));
            lpart += (ps.x + ps.y) + (ps.z + ps.w);   // per-lane partial (g-reduce deferred)
            // P[q=c][kt] bf16 -> LDS (row stride 72 u16 = 144 B, 2-way conflicts only)
            #pragma unroll
            for (int j = 0; j < 4; ++j) {
                short4v w;
                w.x = (short)f2bf(p[j].x); w.y = (short)f2bf(p[j].y);
                w.z = (short)f2bf(p[j].z); w.w = (short)f2bf(p[j].w);
                *(short4v*)(P + c * 72 + j * 16 + g * 4) = w;
            }
            const short8 pf0 = *(const short8*)(P + c * 72 + g * 8);
            const short8 pf1 = *(const short8*)(P + c * 72 + 32 + g * 8);
            // PV: A = V^T rows (d), B = P^T -> D[d][q]
            __builtin_amdgcn_s_setprio(1);
            #pragma unroll
            for (int dt = 0; dt < 4; ++dt) {
                oacc[dt] = MFMA16x16x32(vf0[dt], pf0, oacc[dt], 0, 0, 0);
                oacc[dt] = MFMA16x16x32(vf1[dt], pf1, oacc[dt], 0, 0, 0);
            }
            __builtin_amdgcn_s_setprio(0);
            __syncthreads();   // drains staging (vmcnt 0) + all waves done with buf cur
            cur ^= 1;
        }
        float lsum = lpart;
        lsum += __shfl_xor(lsum, 16);
        lsum += __shfl_xor(lsum, 32);
        const float li = 1.f / lsum;             // lane-local (col=q layout)
        #pragma unroll
        for (int dt = 0; dt < 4; ++dt) {
            short4v o;
            o.x = (short)f2bf(oacc[dt][0] * li);
            o.y = (short)f2bf(oacc[dt][1] * li);
            o.z = (short)f2bf(oacc[dt][2] * li);
            o.w = (short)f2bf(oacc[dt][3] * li);
            *(short4v*)(Ob + (size_t)(b * 1024 + qg) * 768 + h * 64 + dt * 16 + g * 4) = o;
        }
    }
#undef STAGE
}

extern "C" void kernel_launch(void* const* d_in, const int* in_sizes, int n_in,
                              void* d_out, int out_size, void* d_ws, size_t ws_size,
                              hipStream_t stream) {
    const float* hs = (const float*)d_in[0];   // [8,1024,768]
    const float* Wa = (const float*)d_in[1];   // [768,2304]
    const float* ba = (const float*)d_in[2];   // [2304]
    const float* Wp = (const float*)d_in[3];   // [768,768]
    const float* bp = (const float*)d_in[4];   // [768]
    float* out = (float*)d_out;                // out | K | V  (each NOUT fp32)

    u16* ws  = (u16*)d_ws;
    u16* Xbf = ws;                             // [8192][768]
    u16* WaT = Xbf + NOUT;                     // [2304][768]
    u16* WpT = WaT + 768 * 2304;               // [768][768]
    u16* Qbf = WpT + 768 * 768;                // [B,H,T,64] (pre-scaled by 0.125*log2e)
    u16* Kbf = Qbf + NOUT;                     // [B,H,T,64]
    u16* VTb = Kbf + NOUT;                     // [B,H,64,T]
    u16* Obf = VTb + NOUT;                     // [8192][768]

    cvt_bf16_kernel<<<NOUT / 1024, 256, 0, stream>>>(hs, Xbf, NOUT);
    transpose_bf16_kernel<<<dim3(2304 / 32, 768 / 32), 256, 0, stream>>>(Wa, WaT, 768, 2304);
    transpose_bf16_kernel<<<dim3(768 / 32, 768 / 32), 256, 0, stream>>>(Wp, WpT, 768, 768);
    gemm_k768_kernel<0><<<dim3(64, 18), 256, 0, stream>>>(
        Xbf, WaT, ba, Qbf, Kbf, out + NOUT, out + 2 * (size_t)NOUT, nullptr);
    transpose_v_kernel<<<dim3(32, 2, 96), 256, 0, stream>>>(out + 2 * (size_t)NOUT, VTb);
    attn_kernel<<<dim3(96, 8), 256, 0, stream>>>(Qbf, Kbf, VTb, Obf);
    gemm_k768_kernel<1><<<dim3(64, 6), 256, 0, stream>>>(
        Obf, WpT, bp, nullptr, nullptr, nullptr, nullptr, out);
}